// Round 4
// baseline (1317.898 us; speedup 1.0000x reference)
//
#include <hip/hip_runtime.h>
#include <math.h>

#define N_NODES 100000
#define N_EDGES 1600000
#define HEADS 4
#define NB ((N_NODES + 255) / 256)   // 391 scan blocks

// ---------------- CSR build kernels ----------------

__global__ void zero_int_kernel(int* __restrict__ ptr, int n) {
    int i = blockIdx.x * blockDim.x + threadIdx.x;
    if (i < n) ptr[i] = 0;
}

__global__ void hist_kernel(const int* __restrict__ dst, int* __restrict__ cnt) {
    int e = blockIdx.x * blockDim.x + threadIdx.x;
    if (e < N_EDGES) atomicAdd(&cnt[dst[e]], 1);
}

// per-block exclusive scan of cnt -> rowptr (block-local), block totals -> blockSums
__global__ __launch_bounds__(256) void scan_block_kernel(
        const int* __restrict__ cnt, int* __restrict__ rowptr, int* __restrict__ blockSums) {
    __shared__ int tmp[256];
    int i = blockIdx.x * 256 + threadIdx.x;
    int v = (i < N_NODES) ? cnt[i] : 0;
    tmp[threadIdx.x] = v;
    __syncthreads();
    for (int off = 1; off < 256; off <<= 1) {
        int t = (threadIdx.x >= off) ? tmp[threadIdx.x - off] : 0;
        __syncthreads();
        tmp[threadIdx.x] += t;
        __syncthreads();
    }
    if (i < N_NODES) rowptr[i] = tmp[threadIdx.x] - v;        // exclusive, block-local
    if (threadIdx.x == 255) blockSums[blockIdx.x] = tmp[255]; // inclusive block total
}

// single-block exclusive scan of blockSums (NB=391 <= 512)
__global__ __launch_bounds__(512) void scan_sums_kernel(int* __restrict__ blockSums) {
    __shared__ int tmp[512];
    int i = threadIdx.x;
    int v = (i < NB) ? blockSums[i] : 0;
    tmp[i] = v;
    __syncthreads();
    for (int off = 1; off < 512; off <<= 1) {
        int t = (i >= off) ? tmp[i - off] : 0;
        __syncthreads();
        tmp[i] += t;
        __syncthreads();
    }
    if (i < NB) blockSums[i] = tmp[i] - v;                    // exclusive
}

__global__ __launch_bounds__(256) void add_offsets_kernel(
        int* __restrict__ rowptr, const int* __restrict__ blockSums) {
    int i = blockIdx.x * 256 + threadIdx.x;
    if (i < N_NODES) rowptr[i] += blockSums[blockIdx.x];
    if (i == 0) rowptr[N_NODES] = N_EDGES;
}

__global__ void scatter_kernel(const int* __restrict__ src, const int* __restrict__ dst,
                               const int* __restrict__ rowptr, int* __restrict__ cnt,
                               int* __restrict__ csr_src, int* __restrict__ csr_dst) {
    int e = blockIdx.x * blockDim.x + threadIdx.x;
    if (e >= N_EDGES) return;
    int d = dst[e];
    int pos = rowptr[d] + atomicAdd(&cnt[d], 1);
    csr_src[pos] = src[e];
    csr_dst[pos] = d;
}

__global__ void invdeg_kernel(const int* __restrict__ rowptr, float* __restrict__ inv_deg) {
    int n = blockIdx.x * blockDim.x + threadIdx.x;
    if (n >= N_NODES) return;
    float d = (float)(rowptr[n + 1] - rowptr[n]);
    inv_deg[n] = 1.0f / fmaxf(d, 1.0f);
}

// ---------------- p = h @ U  [N,4] ----------------

template<int FIN>
__global__ __launch_bounds__(256) void p_kernel(
        const float* __restrict__ h, const float* __restrict__ U,  // [FIN,4]
        float* __restrict__ p)                                     // [N,4]
{
    int n = blockIdx.x * blockDim.x + threadIdx.x;
    if (n >= N_NODES) return;
    float a0 = 0, a1 = 0, a2 = 0, a3 = 0;
    const float* hr = h + (size_t)n * FIN;
    #pragma unroll
    for (int f = 0; f < FIN; f++) {
        float xv = hr[f];
        a0 += xv * U[f * 4 + 0];
        a1 += xv * U[f * 4 + 1];
        a2 += xv * U[f * 4 + 2];
        a3 += xv * U[f * 4 + 3];
    }
    *(float4*)(p + (size_t)n * 4) = make_float4(a0, a1, a2, a3);
}

// ---------------- q per CSR edge: softmax(p_s - p_d + c) * inv_deg[d] ----------------

__global__ __launch_bounds__(256) void q_kernel(
        const int* __restrict__ csr_src, const int* __restrict__ csr_dst,
        const float* __restrict__ p, const float* __restrict__ c,
        const float* __restrict__ inv_deg,
        float4* __restrict__ q_csr)
{
    int k = blockIdx.x * blockDim.x + threadIdx.x;
    if (k >= N_EDGES) return;
    int s = csr_src[k], d = csr_dst[k];
    float4 ps = *(const float4*)(p + (size_t)s * 4);
    float4 pd = *(const float4*)(p + (size_t)d * 4);
    float l0 = ps.x - pd.x + c[0];
    float l1 = ps.y - pd.y + c[1];
    float l2 = ps.z - pd.z + c[2];
    float l3 = ps.w - pd.w + c[3];
    float m = fmaxf(fmaxf(l0, l1), fmaxf(l2, l3));
    float q0 = expf(l0 - m), q1 = expf(l1 - m), q2 = expf(l2 - m), q3 = expf(l3 - m);
    float inv = inv_deg[d] / (q0 + q1 + q2 + q3);
    q_csr[k] = make_float4(q0 * inv, q1 * inv, q2 * inv, q3 * inv);
}

// ---------------- z gather: z[n][h*FIN+f] = sum_k q[k][h] * hprev[src_k][f] ----------------

template<int FIN>
__global__ __launch_bounds__(256) void zgather_kernel(
        const int* __restrict__ rowptr, const int* __restrict__ csr_src,
        const float4* __restrict__ q_csr,
        const float* __restrict__ hprev,   // [N, FIN]
        float* __restrict__ z)             // [N, 4*FIN]
{
    int t = blockIdx.x * blockDim.x + threadIdx.x;
    int n = t / FIN;
    int f = t - n * FIN;
    if (n >= N_NODES) return;
    int beg = rowptr[n], end = rowptr[n + 1];
    float a0 = 0, a1 = 0, a2 = 0, a3 = 0;
    for (int k = beg; k < end; k++) {
        int s = csr_src[k];              // broadcast within FIN-lane group
        float4 q = q_csr[k];             // broadcast
        float xv = hprev[(size_t)s * FIN + f];  // coalesced FIN-float segment
        a0 += q.x * xv; a1 += q.y * xv; a2 += q.z * xv; a3 += q.w * xv;
    }
    size_t base = (size_t)n * (4 * FIN) + f;
    z[base]           = a0;
    z[base + FIN]     = a1;
    z[base + 2 * FIN] = a2;
    z[base + 3 * FIN] = a3;
}

// ---------------- post: out[n,o] = relu( sum_{h,f} z[n,h*FIN+f]*W[f,h*FOUT+o] + b[o] )
// Tiled: thread = 4 nodes x 4 outputs (16 independent accumulators).
// Per k-quad: 4x ds_read_b128 of W shared across 4 nodes, 4x dwordx4 z, 64 FMA.

template<int FIN, int FOUT>
__global__ __launch_bounds__(256) void post_kernel(
        const float* __restrict__ z,    // [N, 4*FIN]
        const float* __restrict__ W,    // [FIN, 4*FOUT]
        const float* __restrict__ b,    // [FOUT]
        float* __restrict__ out)        // [N, FOUT]
{
    constexpr int OL  = FOUT / 4;       // o-lanes per node
    constexpr int G   = 256 / OL;       // node-groups per block
    constexpr int NPB = 4 * G;          // nodes per block
    constexpr int WSZ = FIN * 4 * FOUT;
    __shared__ float Ws[WSZ];
    for (int i = threadIdx.x; i < WSZ; i += 256) Ws[i] = W[i];
    __syncthreads();

    int ol = threadIdx.x % OL;
    int g  = threadIdx.x / OL;
    int n0 = blockIdx.x * NPB + g * 4;

    float4 bv = *(const float4*)(b + 4 * ol);
    float4 acc[4];
    const float* zr[4];
    #pragma unroll
    for (int j = 0; j < 4; j++) {
        acc[j] = bv;
        int nn = n0 + j; if (nn > N_NODES - 1) nn = N_NODES - 1;  // clamp for safe loads
        zr[j] = z + (size_t)nn * (4 * FIN);
    }

    #pragma unroll
    for (int h = 0; h < 4; h++) {
        #pragma unroll
        for (int f4 = 0; f4 < FIN; f4 += 4) {
            float4 zv[4];
            #pragma unroll
            for (int j = 0; j < 4; j++)
                zv[j] = *(const float4*)(zr[j] + h * FIN + f4);
            #pragma unroll
            for (int jj = 0; jj < 4; jj++) {
                float4 wv = *(const float4*)(Ws + (f4 + jj) * (4 * FOUT) + h * FOUT + 4 * ol);
                #pragma unroll
                for (int j = 0; j < 4; j++) {
                    float s = (&zv[j].x)[jj];
                    acc[j].x += s * wv.x;
                    acc[j].y += s * wv.y;
                    acc[j].z += s * wv.z;
                    acc[j].w += s * wv.w;
                }
            }
        }
    }

    #pragma unroll
    for (int j = 0; j < 4; j++) {
        int nn = n0 + j;
        if (nn < N_NODES) {
            float4 r;
            r.x = fmaxf(acc[j].x, 0.0f);
            r.y = fmaxf(acc[j].y, 0.0f);
            r.z = fmaxf(acc[j].z, 0.0f);
            r.w = fmaxf(acc[j].w, 0.0f);
            *(float4*)(out + (size_t)nn * FOUT + 4 * ol) = r;
        }
    }
}

// ---------------- fused linear tail: 64->32->16->8->4->1, relu..., sigmoid ----------------

__global__ __launch_bounds__(256) void tail_kernel(
        const float* __restrict__ h,   // [N, 64]
        const float* __restrict__ lw1, const float* __restrict__ lb1,
        const float* __restrict__ lw2, const float* __restrict__ lb2,
        const float* __restrict__ lw3, const float* __restrict__ lb3,
        const float* __restrict__ lw4, const float* __restrict__ lb4,
        const float* __restrict__ lw5, const float* __restrict__ lb5,
        float* __restrict__ out)
{
    __shared__ float w1[64 * 32], w2[32 * 16], w3[16 * 8], w4[8 * 4], w5[4];
    __shared__ float B1[32], B2[16], B3[8], B4[4], B5[1];
    for (int i = threadIdx.x; i < 64 * 32; i += blockDim.x) w1[i] = lw1[i];
    for (int i = threadIdx.x; i < 32 * 16; i += blockDim.x) w2[i] = lw2[i];
    for (int i = threadIdx.x; i < 16 * 8;  i += blockDim.x) w3[i] = lw3[i];
    for (int i = threadIdx.x; i < 8 * 4;   i += blockDim.x) w4[i] = lw4[i];
    for (int i = threadIdx.x; i < 4;       i += blockDim.x) w5[i] = lw5[i];
    for (int i = threadIdx.x; i < 32; i += blockDim.x) B1[i] = lb1[i];
    for (int i = threadIdx.x; i < 16; i += blockDim.x) B2[i] = lb2[i];
    for (int i = threadIdx.x; i < 8;  i += blockDim.x) B3[i] = lb3[i];
    for (int i = threadIdx.x; i < 4;  i += blockDim.x) B4[i] = lb4[i];
    if (threadIdx.x == 0) B5[0] = lb5[0];
    __syncthreads();

    int n = blockIdx.x * blockDim.x + threadIdx.x;
    if (n >= N_NODES) return;

    float a[64];
    #pragma unroll
    for (int i = 0; i < 64; i++) a[i] = h[(size_t)n * 64 + i];

    float t1[32];
    for (int o = 0; o < 32; o++) {
        float acc = B1[o];
        #pragma unroll
        for (int i = 0; i < 64; i++) acc += a[i] * w1[i * 32 + o];
        t1[o] = fmaxf(acc, 0.0f);
    }
    float t2[16];
    for (int o = 0; o < 16; o++) {
        float acc = B2[o];
        #pragma unroll
        for (int i = 0; i < 32; i++) acc += t1[i] * w2[i * 16 + o];
        t2[o] = fmaxf(acc, 0.0f);
    }
    float t3[8];
    for (int o = 0; o < 8; o++) {
        float acc = B3[o];
        #pragma unroll
        for (int i = 0; i < 16; i++) acc += t2[i] * w3[i * 8 + o];
        t3[o] = fmaxf(acc, 0.0f);
    }
    float t4[4];
    for (int o = 0; o < 4; o++) {
        float acc = B4[o];
        #pragma unroll
        for (int i = 0; i < 8; i++) acc += t3[i] * w4[i * 4 + o];
        t4[o] = fmaxf(acc, 0.0f);
    }
    float zf = B5[0];
    #pragma unroll
    for (int i = 0; i < 4; i++) zf += t4[i] * w5[i];
    out[n] = 1.0f / (1.0f + expf(-zf));
}

// ---------------- host launch ----------------

extern "C" void kernel_launch(void* const* d_in, const int* in_sizes, int n_in,
                              void* d_out, int out_size, void* d_ws, size_t ws_size,
                              hipStream_t stream) {
    const float* x   = (const float*)d_in[0];
    const int*   ei  = (const int*)d_in[1];
    const int*   src = ei;
    const int*   dst = ei + N_EDGES;
    const float* U1 = (const float*)d_in[2];  const float* c1 = (const float*)d_in[3];
    const float* W1 = (const float*)d_in[4];  const float* b1 = (const float*)d_in[5];
    const float* U2 = (const float*)d_in[6];  const float* c2 = (const float*)d_in[7];
    const float* W2 = (const float*)d_in[8];  const float* b2 = (const float*)d_in[9];
    const float* U3 = (const float*)d_in[10]; const float* c3 = (const float*)d_in[11];
    const float* W3 = (const float*)d_in[12]; const float* b3 = (const float*)d_in[13];
    const float* lw1 = (const float*)d_in[14]; const float* lb1 = (const float*)d_in[15];
    const float* lw2 = (const float*)d_in[16]; const float* lb2 = (const float*)d_in[17];
    const float* lw3 = (const float*)d_in[18]; const float* lb3 = (const float*)d_in[19];
    const float* lw4 = (const float*)d_in[20]; const float* lb4 = (const float*)d_in[21];
    const float* lw5 = (const float*)d_in[22]; const float* lb5 = (const float*)d_in[23];

    char* ws = (char*)d_ws;
    size_t off = 0;
    auto alloc = [&](size_t bytes) -> void* {
        void* ptr = (void*)(ws + off);
        off += (bytes + 255) & ~(size_t)255;
        return ptr;
    };
    int*    cnt       = (int*)alloc((size_t)N_NODES * 4);
    int*    rowptr    = (int*)alloc(((size_t)N_NODES + 1) * 4);
    int*    blockSums = (int*)alloc(512 * 4);
    int*    csr_src   = (int*)alloc((size_t)N_EDGES * 4);
    int*    csr_dst   = (int*)alloc((size_t)N_EDGES * 4);
    float*  inv_deg   = (float*)alloc((size_t)N_NODES * 4);
    float*  p         = (float*)alloc((size_t)N_NODES * 4 * 4);    // [N,4]
    float4* q_csr     = (float4*)alloc((size_t)N_EDGES * 16);      // [E,4]
    float*  z         = (float*)alloc((size_t)N_NODES * 128 * 4);  // [N,128] max
    float*  h1        = (float*)alloc((size_t)N_NODES * 16 * 4);
    float*  h2        = (float*)alloc((size_t)N_NODES * 32 * 4);
    float*  h3        = (float*)alloc((size_t)N_NODES * 64 * 4);
    (void)ws_size;

    const int B = 256;
    int gN = (N_NODES + B - 1) / B;   // == NB
    int gE = (N_EDGES + B - 1) / B;

    // ---- build dst-CSR ----
    zero_int_kernel<<<gN, B, 0, stream>>>(cnt, N_NODES);
    hist_kernel<<<gE, B, 0, stream>>>(dst, cnt);
    scan_block_kernel<<<NB, 256, 0, stream>>>(cnt, rowptr, blockSums);
    scan_sums_kernel<<<1, 512, 0, stream>>>(blockSums);
    add_offsets_kernel<<<NB, 256, 0, stream>>>(rowptr, blockSums);
    zero_int_kernel<<<gN, B, 0, stream>>>(cnt, N_NODES);
    scatter_kernel<<<gE, B, 0, stream>>>(src, dst, rowptr, cnt, csr_src, csr_dst);
    invdeg_kernel<<<gN, B, 0, stream>>>(rowptr, inv_deg);

    // nodes-per-block for the tiled post kernels
    const int NPB1 = 4 * (256 / (16 / 4));   // 256
    const int NPB2 = 4 * (256 / (32 / 4));   // 128
    const int NPB3 = 4 * (256 / (64 / 4));   // 64

    // ---- conv1: 16 -> 16 ----
    p_kernel<16><<<gN, B, 0, stream>>>(x, U1, p);
    q_kernel<<<gE, B, 0, stream>>>(csr_src, csr_dst, p, c1, inv_deg, q_csr);
    zgather_kernel<16><<<(N_NODES * 16 + B - 1) / B, B, 0, stream>>>(rowptr, csr_src, q_csr, x, z);
    post_kernel<16, 16><<<(N_NODES + NPB1 - 1) / NPB1, B, 0, stream>>>(z, W1, b1, h1);

    // ---- conv2: 16 -> 32 ----
    p_kernel<16><<<gN, B, 0, stream>>>(h1, U2, p);
    q_kernel<<<gE, B, 0, stream>>>(csr_src, csr_dst, p, c2, inv_deg, q_csr);
    zgather_kernel<16><<<(N_NODES * 16 + B - 1) / B, B, 0, stream>>>(rowptr, csr_src, q_csr, h1, z);
    post_kernel<16, 32><<<(N_NODES + NPB2 - 1) / NPB2, B, 0, stream>>>(z, W2, b2, h2);

    // ---- conv3: 32 -> 64 ----
    p_kernel<32><<<gN, B, 0, stream>>>(h2, U3, p);
    q_kernel<<<gE, B, 0, stream>>>(csr_src, csr_dst, p, c3, inv_deg, q_csr);
    zgather_kernel<32><<<(N_NODES * 32 + B - 1) / B, B, 0, stream>>>(rowptr, csr_src, q_csr, h2, z);
    post_kernel<32, 64><<<(N_NODES + NPB3 - 1) / NPB3, B, 0, stream>>>(z, W3, b3, h3);

    // ---- tail MLP ----
    tail_kernel<<<gN, B, 0, stream>>>(h3, lw1, lb1, lw2, lb2, lw3, lb3,
                                      lw4, lb4, lw5, lb5, (float*)d_out);
}

// Round 5
// 644.592 us; speedup vs baseline: 2.0445x; 2.0445x over previous
//
#include <hip/hip_runtime.h>
#include <math.h>

#define N_NODES 100000
#define N_EDGES 1600000
#define HEADS 4
#define NB ((N_NODES + 255) / 256)   // 391 scan blocks

// ---------------- CSR build kernels ----------------

__global__ void zero_int_kernel(int* __restrict__ ptr, int n) {
    int i = blockIdx.x * blockDim.x + threadIdx.x;
    if (i < n) ptr[i] = 0;
}

__global__ void hist_kernel(const int* __restrict__ dst, int* __restrict__ cnt) {
    int e = blockIdx.x * blockDim.x + threadIdx.x;
    if (e < N_EDGES) atomicAdd(&cnt[dst[e]], 1);
}

// per-block exclusive scan of cnt -> rowptr (block-local), block totals -> blockSums
__global__ __launch_bounds__(256) void scan_block_kernel(
        const int* __restrict__ cnt, int* __restrict__ rowptr, int* __restrict__ blockSums) {
    __shared__ int tmp[256];
    int i = blockIdx.x * 256 + threadIdx.x;
    int v = (i < N_NODES) ? cnt[i] : 0;
    tmp[threadIdx.x] = v;
    __syncthreads();
    for (int off = 1; off < 256; off <<= 1) {
        int t = (threadIdx.x >= off) ? tmp[threadIdx.x - off] : 0;
        __syncthreads();
        tmp[threadIdx.x] += t;
        __syncthreads();
    }
    if (i < N_NODES) rowptr[i] = tmp[threadIdx.x] - v;        // exclusive, block-local
    if (threadIdx.x == 255) blockSums[blockIdx.x] = tmp[255]; // inclusive block total
}

// single-block exclusive scan of blockSums (NB=391 <= 512)
__global__ __launch_bounds__(512) void scan_sums_kernel(int* __restrict__ blockSums) {
    __shared__ int tmp[512];
    int i = threadIdx.x;
    int v = (i < NB) ? blockSums[i] : 0;
    tmp[i] = v;
    __syncthreads();
    for (int off = 1; off < 512; off <<= 1) {
        int t = (i >= off) ? tmp[i - off] : 0;
        __syncthreads();
        tmp[i] += t;
        __syncthreads();
    }
    if (i < NB) blockSums[i] = tmp[i] - v;                    // exclusive
}

__global__ __launch_bounds__(256) void add_offsets_kernel(
        int* __restrict__ rowptr, const int* __restrict__ blockSums) {
    int i = blockIdx.x * 256 + threadIdx.x;
    if (i < N_NODES) rowptr[i] += blockSums[blockIdx.x];
    if (i == 0) rowptr[N_NODES] = N_EDGES;
}

__global__ void scatter_kernel(const int* __restrict__ src, const int* __restrict__ dst,
                               const int* __restrict__ rowptr, int* __restrict__ cnt,
                               int* __restrict__ csr_src, int* __restrict__ csr_dst) {
    int e = blockIdx.x * blockDim.x + threadIdx.x;
    if (e >= N_EDGES) return;
    int d = dst[e];
    int pos = rowptr[d] + atomicAdd(&cnt[d], 1);
    csr_src[pos] = src[e];
    csr_dst[pos] = d;
}

__global__ void invdeg_kernel(const int* __restrict__ rowptr, float* __restrict__ inv_deg) {
    int n = blockIdx.x * blockDim.x + threadIdx.x;
    if (n >= N_NODES) return;
    float d = (float)(rowptr[n + 1] - rowptr[n]);
    inv_deg[n] = 1.0f / fmaxf(d, 1.0f);
}

// ---------------- p = h @ U  [N,4] ----------------

template<int FIN>
__global__ __launch_bounds__(256) void p_kernel(
        const float* __restrict__ h, const float* __restrict__ U,  // [FIN,4]
        float* __restrict__ p)                                     // [N,4]
{
    int n = blockIdx.x * blockDim.x + threadIdx.x;
    if (n >= N_NODES) return;
    float a0 = 0, a1 = 0, a2 = 0, a3 = 0;
    const float* hr = h + (size_t)n * FIN;
    #pragma unroll
    for (int f = 0; f < FIN; f++) {
        float xv = hr[f];
        a0 += xv * U[f * 4 + 0];
        a1 += xv * U[f * 4 + 1];
        a2 += xv * U[f * 4 + 2];
        a3 += xv * U[f * 4 + 3];
    }
    *(float4*)(p + (size_t)n * 4) = make_float4(a0, a1, a2, a3);
}

// ---------------- q per CSR edge: softmax(p_s - p_d + c) * inv_deg[d] ----------------

__global__ __launch_bounds__(256) void q_kernel(
        const int* __restrict__ csr_src, const int* __restrict__ csr_dst,
        const float* __restrict__ p, const float* __restrict__ c,
        const float* __restrict__ inv_deg,
        float4* __restrict__ q_csr)
{
    int k = blockIdx.x * blockDim.x + threadIdx.x;
    if (k >= N_EDGES) return;
    int s = csr_src[k], d = csr_dst[k];
    float4 ps = *(const float4*)(p + (size_t)s * 4);
    float4 pd = *(const float4*)(p + (size_t)d * 4);
    float l0 = ps.x - pd.x + c[0];
    float l1 = ps.y - pd.y + c[1];
    float l2 = ps.z - pd.z + c[2];
    float l3 = ps.w - pd.w + c[3];
    float m = fmaxf(fmaxf(l0, l1), fmaxf(l2, l3));
    float q0 = expf(l0 - m), q1 = expf(l1 - m), q2 = expf(l2 - m), q3 = expf(l3 - m);
    float inv = inv_deg[d] / (q0 + q1 + q2 + q3);
    q_csr[k] = make_float4(q0 * inv, q1 * inv, q2 * inv, q3 * inv);
}

// ---------------- z gather: z[n][h*FIN+f] = sum_k q[k][h] * hprev[src_k][f] ----------------

template<int FIN>
__global__ __launch_bounds__(256) void zgather_kernel(
        const int* __restrict__ rowptr, const int* __restrict__ csr_src,
        const float4* __restrict__ q_csr,
        const float* __restrict__ hprev,   // [N, FIN]
        float* __restrict__ z)             // [N, 4*FIN]
{
    int t = blockIdx.x * blockDim.x + threadIdx.x;
    int n = t / FIN;
    int f = t - n * FIN;
    if (n >= N_NODES) return;
    int beg = rowptr[n], end = rowptr[n + 1];
    float a0 = 0, a1 = 0, a2 = 0, a3 = 0;
    for (int k = beg; k < end; k++) {
        int s = csr_src[k];              // broadcast within FIN-lane group
        float4 q = q_csr[k];             // broadcast
        float xv = hprev[(size_t)s * FIN + f];  // coalesced FIN-float segment
        a0 += q.x * xv; a1 += q.y * xv; a2 += q.z * xv; a3 += q.w * xv;
    }
    size_t base = (size_t)n * (4 * FIN) + f;
    z[base]           = a0;
    z[base + FIN]     = a1;
    z[base + 2 * FIN] = a2;
    z[base + 3 * FIN] = a3;
}

// ---------------- post: out[n,o] = relu( sum_k z[n,k]*Wp[k,o] + b[o] ),  k = h*FIN+f
// Tiled: thread = 4 nodes x 4 outputs (16 independent FMA chains).
// W pre-permuted into LDS k-major so the k-loop is linear; limited unroll
// + __launch_bounds__(256,4) keep VGPRs bounded (R4 full-unroll spilled).

template<int FIN, int FOUT>
__global__ __launch_bounds__(256, 4) void post_kernel(
        const float* __restrict__ z,    // [N, 4*FIN]
        const float* __restrict__ W,    // [FIN, 4*FOUT]
        const float* __restrict__ b,    // [FOUT]
        float* __restrict__ out)        // [N, FOUT]
{
    constexpr int K   = 4 * FIN;        // contraction length
    constexpr int OL  = FOUT / 4;       // o-lanes per node
    constexpr int NPB = 4 * (256 / OL); // nodes per block
    constexpr int WSZ = FIN * 4 * FOUT;
    __shared__ float Wp[WSZ];           // [K][FOUT], k = h*FIN+f
    for (int i = threadIdx.x; i < WSZ; i += 256) {
        int f = i / (4 * FOUT);
        int r = i - f * (4 * FOUT);
        int h = r / FOUT;
        int o = r - h * FOUT;
        Wp[(h * FIN + f) * FOUT + o] = W[i];
    }
    __syncthreads();

    int ol = threadIdx.x % OL;
    int g  = threadIdx.x / OL;
    int n0 = blockIdx.x * NPB + g * 4;

    float4 bv = *(const float4*)(b + 4 * ol);
    float4 acc[4];
    const float* zr[4];
    #pragma unroll
    for (int j = 0; j < 4; j++) {
        acc[j] = make_float4(0.f, 0.f, 0.f, 0.f);
        int nn = n0 + j; if (nn > N_NODES - 1) nn = N_NODES - 1;  // clamp for safe loads
        zr[j] = z + (size_t)nn * K;
    }

    #pragma unroll 2
    for (int kq = 0; kq < K / 4; kq++) {
        float4 zv[4];
        #pragma unroll
        for (int j = 0; j < 4; j++)
            zv[j] = *(const float4*)(zr[j] + 4 * kq);
        #pragma unroll
        for (int jj = 0; jj < 4; jj++) {
            float4 wv = *(const float4*)(Wp + (4 * kq + jj) * FOUT + 4 * ol);
            #pragma unroll
            for (int j = 0; j < 4; j++) {
                float s = (&zv[j].x)[jj];
                acc[j].x += s * wv.x;
                acc[j].y += s * wv.y;
                acc[j].z += s * wv.z;
                acc[j].w += s * wv.w;
            }
        }
    }

    #pragma unroll
    for (int j = 0; j < 4; j++) {
        int nn = n0 + j;
        if (nn < N_NODES) {
            float4 r;
            r.x = fmaxf(acc[j].x + bv.x, 0.0f);
            r.y = fmaxf(acc[j].y + bv.y, 0.0f);
            r.z = fmaxf(acc[j].z + bv.z, 0.0f);
            r.w = fmaxf(acc[j].w + bv.w, 0.0f);
            *(float4*)(out + (size_t)nn * FOUT + 4 * ol) = r;
        }
    }
}

// ---------------- fused linear tail: 64->32->16->8->4->1, relu..., sigmoid ----------------

__global__ __launch_bounds__(256) void tail_kernel(
        const float* __restrict__ h,   // [N, 64]
        const float* __restrict__ lw1, const float* __restrict__ lb1,
        const float* __restrict__ lw2, const float* __restrict__ lb2,
        const float* __restrict__ lw3, const float* __restrict__ lb3,
        const float* __restrict__ lw4, const float* __restrict__ lb4,
        const float* __restrict__ lw5, const float* __restrict__ lb5,
        float* __restrict__ out)
{
    __shared__ float w1[64 * 32], w2[32 * 16], w3[16 * 8], w4[8 * 4], w5[4];
    __shared__ float B1[32], B2[16], B3[8], B4[4], B5[1];
    for (int i = threadIdx.x; i < 64 * 32; i += blockDim.x) w1[i] = lw1[i];
    for (int i = threadIdx.x; i < 32 * 16; i += blockDim.x) w2[i] = lw2[i];
    for (int i = threadIdx.x; i < 16 * 8;  i += blockDim.x) w3[i] = lw3[i];
    for (int i = threadIdx.x; i < 8 * 4;   i += blockDim.x) w4[i] = lw4[i];
    for (int i = threadIdx.x; i < 4;       i += blockDim.x) w5[i] = lw5[i];
    for (int i = threadIdx.x; i < 32; i += blockDim.x) B1[i] = lb1[i];
    for (int i = threadIdx.x; i < 16; i += blockDim.x) B2[i] = lb2[i];
    for (int i = threadIdx.x; i < 8;  i += blockDim.x) B3[i] = lb3[i];
    for (int i = threadIdx.x; i < 4;  i += blockDim.x) B4[i] = lb4[i];
    if (threadIdx.x == 0) B5[0] = lb5[0];
    __syncthreads();

    int n = blockIdx.x * blockDim.x + threadIdx.x;
    if (n >= N_NODES) return;

    float a[64];
    #pragma unroll
    for (int i = 0; i < 64; i++) a[i] = h[(size_t)n * 64 + i];

    float t1[32];
    for (int o = 0; o < 32; o++) {
        float acc = B1[o];
        #pragma unroll
        for (int i = 0; i < 64; i++) acc += a[i] * w1[i * 32 + o];
        t1[o] = fmaxf(acc, 0.0f);
    }
    float t2[16];
    for (int o = 0; o < 16; o++) {
        float acc = B2[o];
        #pragma unroll
        for (int i = 0; i < 32; i++) acc += t1[i] * w2[i * 16 + o];
        t2[o] = fmaxf(acc, 0.0f);
    }
    float t3[8];
    for (int o = 0; o < 8; o++) {
        float acc = B3[o];
        #pragma unroll
        for (int i = 0; i < 16; i++) acc += t2[i] * w3[i * 8 + o];
        t3[o] = fmaxf(acc, 0.0f);
    }
    float t4[4];
    for (int o = 0; o < 4; o++) {
        float acc = B4[o];
        #pragma unroll
        for (int i = 0; i < 8; i++) acc += t3[i] * w4[i * 4 + o];
        t4[o] = fmaxf(acc, 0.0f);
    }
    float zf = B5[0];
    #pragma unroll
    for (int i = 0; i < 4; i++) zf += t4[i] * w5[i];
    out[n] = 1.0f / (1.0f + expf(-zf));
}

// ---------------- host launch ----------------

extern "C" void kernel_launch(void* const* d_in, const int* in_sizes, int n_in,
                              void* d_out, int out_size, void* d_ws, size_t ws_size,
                              hipStream_t stream) {
    const float* x   = (const float*)d_in[0];
    const int*   ei  = (const int*)d_in[1];
    const int*   src = ei;
    const int*   dst = ei + N_EDGES;
    const float* U1 = (const float*)d_in[2];  const float* c1 = (const float*)d_in[3];
    const float* W1 = (const float*)d_in[4];  const float* b1 = (const float*)d_in[5];
    const float* U2 = (const float*)d_in[6];  const float* c2 = (const float*)d_in[7];
    const float* W2 = (const float*)d_in[8];  const float* b2 = (const float*)d_in[9];
    const float* U3 = (const float*)d_in[10]; const float* c3 = (const float*)d_in[11];
    const float* W3 = (const float*)d_in[12]; const float* b3 = (const float*)d_in[13];
    const float* lw1 = (const float*)d_in[14]; const float* lb1 = (const float*)d_in[15];
    const float* lw2 = (const float*)d_in[16]; const float* lb2 = (const float*)d_in[17];
    const float* lw3 = (const float*)d_in[18]; const float* lb3 = (const float*)d_in[19];
    const float* lw4 = (const float*)d_in[20]; const float* lb4 = (const float*)d_in[21];
    const float* lw5 = (const float*)d_in[22]; const float* lb5 = (const float*)d_in[23];

    char* ws = (char*)d_ws;
    size_t off = 0;
    auto alloc = [&](size_t bytes) -> void* {
        void* ptr = (void*)(ws + off);
        off += (bytes + 255) & ~(size_t)255;
        return ptr;
    };
    int*    cnt       = (int*)alloc((size_t)N_NODES * 4);
    int*    rowptr    = (int*)alloc(((size_t)N_NODES + 1) * 4);
    int*    blockSums = (int*)alloc(512 * 4);
    int*    csr_src   = (int*)alloc((size_t)N_EDGES * 4);
    int*    csr_dst   = (int*)alloc((size_t)N_EDGES * 4);
    float*  inv_deg   = (float*)alloc((size_t)N_NODES * 4);
    float*  p         = (float*)alloc((size_t)N_NODES * 4 * 4);    // [N,4]
    float4* q_csr     = (float4*)alloc((size_t)N_EDGES * 16);      // [E,4]
    float*  z         = (float*)alloc((size_t)N_NODES * 128 * 4);  // [N,128] max
    float*  h1        = (float*)alloc((size_t)N_NODES * 16 * 4);
    float*  h2        = (float*)alloc((size_t)N_NODES * 32 * 4);
    float*  h3        = (float*)alloc((size_t)N_NODES * 64 * 4);
    (void)ws_size;

    const int B = 256;
    int gN = (N_NODES + B - 1) / B;   // == NB
    int gE = (N_EDGES + B - 1) / B;

    // ---- build dst-CSR ----
    zero_int_kernel<<<gN, B, 0, stream>>>(cnt, N_NODES);
    hist_kernel<<<gE, B, 0, stream>>>(dst, cnt);
    scan_block_kernel<<<NB, 256, 0, stream>>>(cnt, rowptr, blockSums);
    scan_sums_kernel<<<1, 512, 0, stream>>>(blockSums);
    add_offsets_kernel<<<NB, 256, 0, stream>>>(rowptr, blockSums);
    zero_int_kernel<<<gN, B, 0, stream>>>(cnt, N_NODES);
    scatter_kernel<<<gE, B, 0, stream>>>(src, dst, rowptr, cnt, csr_src, csr_dst);
    invdeg_kernel<<<gN, B, 0, stream>>>(rowptr, inv_deg);

    // nodes-per-block for the tiled post kernels
    const int NPB1 = 4 * (256 / (16 / 4));   // 256
    const int NPB2 = 4 * (256 / (32 / 4));   // 128
    const int NPB3 = 4 * (256 / (64 / 4));   // 64

    // ---- conv1: 16 -> 16 ----
    p_kernel<16><<<gN, B, 0, stream>>>(x, U1, p);
    q_kernel<<<gE, B, 0, stream>>>(csr_src, csr_dst, p, c1, inv_deg, q_csr);
    zgather_kernel<16><<<(N_NODES * 16 + B - 1) / B, B, 0, stream>>>(rowptr, csr_src, q_csr, x, z);
    post_kernel<16, 16><<<(N_NODES + NPB1 - 1) / NPB1, B, 0, stream>>>(z, W1, b1, h1);

    // ---- conv2: 16 -> 32 ----
    p_kernel<16><<<gN, B, 0, stream>>>(h1, U2, p);
    q_kernel<<<gE, B, 0, stream>>>(csr_src, csr_dst, p, c2, inv_deg, q_csr);
    zgather_kernel<16><<<(N_NODES * 16 + B - 1) / B, B, 0, stream>>>(rowptr, csr_src, q_csr, h1, z);
    post_kernel<16, 32><<<(N_NODES + NPB2 - 1) / NPB2, B, 0, stream>>>(z, W2, b2, h2);

    // ---- conv3: 32 -> 64 ----
    p_kernel<32><<<gN, B, 0, stream>>>(h2, U3, p);
    q_kernel<<<gE, B, 0, stream>>>(csr_src, csr_dst, p, c3, inv_deg, q_csr);
    zgather_kernel<32><<<(N_NODES * 32 + B - 1) / B, B, 0, stream>>>(rowptr, csr_src, q_csr, h2, z);
    post_kernel<32, 64><<<(N_NODES + NPB3 - 1) / NPB3, B, 0, stream>>>(z, W3, b3, h3);

    // ---- tail MLP ----
    tail_kernel<<<gN, B, 0, stream>>>(h3, lw1, lb1, lw2, lb2, lw3, lb3,
                                      lw4, lb4, lw5, lb5, (float*)d_out);
}

// Round 6
// 629.803 us; speedup vs baseline: 2.0926x; 1.0235x over previous
//
#include <hip/hip_runtime.h>
#include <math.h>

#define N_NODES 100000
#define N_EDGES 1600000
#define HEADS 4
#define NB ((N_NODES + 255) / 256)   // 391 scan blocks

// ---------------- CSR build kernels ----------------

__global__ void zero_int_kernel(int* __restrict__ ptr, int n) {
    int i = blockIdx.x * blockDim.x + threadIdx.x;
    if (i < n) ptr[i] = 0;
}

__global__ void hist_kernel(const int* __restrict__ dst, int* __restrict__ cnt) {
    int e = blockIdx.x * blockDim.x + threadIdx.x;
    if (e < N_EDGES) atomicAdd(&cnt[dst[e]], 1);
}

// per-block exclusive scan of cnt -> rowptr (block-local), block totals -> blockSums
__global__ __launch_bounds__(256) void scan_block_kernel(
        const int* __restrict__ cnt, int* __restrict__ rowptr, int* __restrict__ blockSums) {
    __shared__ int tmp[256];
    int i = blockIdx.x * 256 + threadIdx.x;
    int v = (i < N_NODES) ? cnt[i] : 0;
    tmp[threadIdx.x] = v;
    __syncthreads();
    for (int off = 1; off < 256; off <<= 1) {
        int t = (threadIdx.x >= off) ? tmp[threadIdx.x - off] : 0;
        __syncthreads();
        tmp[threadIdx.x] += t;
        __syncthreads();
    }
    if (i < N_NODES) rowptr[i] = tmp[threadIdx.x] - v;        // exclusive, block-local
    if (threadIdx.x == 255) blockSums[blockIdx.x] = tmp[255]; // inclusive block total
}

// single-block exclusive scan of blockSums (NB=391 <= 512)
__global__ __launch_bounds__(512) void scan_sums_kernel(int* __restrict__ blockSums) {
    __shared__ int tmp[512];
    int i = threadIdx.x;
    int v = (i < NB) ? blockSums[i] : 0;
    tmp[i] = v;
    __syncthreads();
    for (int off = 1; off < 512; off <<= 1) {
        int t = (i >= off) ? tmp[i - off] : 0;
        __syncthreads();
        tmp[i] += t;
        __syncthreads();
    }
    if (i < NB) blockSums[i] = tmp[i] - v;                    // exclusive
}

__global__ __launch_bounds__(256) void add_offsets_kernel(
        int* __restrict__ rowptr, const int* __restrict__ blockSums) {
    int i = blockIdx.x * 256 + threadIdx.x;
    if (i < N_NODES) rowptr[i] += blockSums[blockIdx.x];
    if (i == 0) rowptr[N_NODES] = N_EDGES;
}

// cnt holds deg after hist; atomicSub makes it the scatter cursor (no re-zero).
// Single int2 store per edge: one dirty cache line instead of two.
__global__ void scatter_kernel(const int* __restrict__ src, const int* __restrict__ dst,
                               const int* __restrict__ rowptr, int* __restrict__ cnt,
                               int2* __restrict__ csr_sd) {
    int e = blockIdx.x * blockDim.x + threadIdx.x;
    if (e >= N_EDGES) return;
    int d = dst[e];
    int old = atomicSub(&cnt[d], 1);
    int pos = rowptr[d] + old - 1;
    csr_sd[pos] = make_int2(src[e], d);
}

__global__ void invdeg_kernel(const int* __restrict__ rowptr, float* __restrict__ inv_deg) {
    int n = blockIdx.x * blockDim.x + threadIdx.x;
    if (n >= N_NODES) return;
    float d = (float)(rowptr[n + 1] - rowptr[n]);
    inv_deg[n] = 1.0f / fmaxf(d, 1.0f);
}

// ---------------- p = h @ U  [N,4] ----------------

template<int FIN>
__global__ __launch_bounds__(256) void p_kernel(
        const float* __restrict__ h, const float* __restrict__ U,  // [FIN,4]
        float* __restrict__ p)                                     // [N,4]
{
    int n = blockIdx.x * blockDim.x + threadIdx.x;
    if (n >= N_NODES) return;
    float a0 = 0, a1 = 0, a2 = 0, a3 = 0;
    const float* hr = h + (size_t)n * FIN;
    #pragma unroll
    for (int f = 0; f < FIN; f++) {
        float xv = hr[f];
        a0 += xv * U[f * 4 + 0];
        a1 += xv * U[f * 4 + 1];
        a2 += xv * U[f * 4 + 2];
        a3 += xv * U[f * 4 + 3];
    }
    *(float4*)(p + (size_t)n * 4) = make_float4(a0, a1, a2, a3);
}

// ---------------- q per CSR edge: softmax(p_s - p_d + c) * inv_deg[d] ----------------

__global__ __launch_bounds__(256) void q_kernel(
        const int2* __restrict__ csr_sd,
        const float* __restrict__ p, const float* __restrict__ c,
        const float* __restrict__ inv_deg,
        float4* __restrict__ q_csr)
{
    int k = blockIdx.x * blockDim.x + threadIdx.x;
    if (k >= N_EDGES) return;
    int2 sd = csr_sd[k];
    int s = sd.x, d = sd.y;
    float4 ps = *(const float4*)(p + (size_t)s * 4);
    float4 pd = *(const float4*)(p + (size_t)d * 4);
    float l0 = ps.x - pd.x + c[0];
    float l1 = ps.y - pd.y + c[1];
    float l2 = ps.z - pd.z + c[2];
    float l3 = ps.w - pd.w + c[3];
    float m = fmaxf(fmaxf(l0, l1), fmaxf(l2, l3));
    float q0 = expf(l0 - m), q1 = expf(l1 - m), q2 = expf(l2 - m), q3 = expf(l3 - m);
    float inv = inv_deg[d] / (q0 + q1 + q2 + q3);
    q_csr[k] = make_float4(q0 * inv, q1 * inv, q2 * inv, q3 * inv);
}

// ---------------- z gather: z[n][h*FIN+f] = sum_k q[k][h] * hprev[src_k][f] ----------------

template<int FIN>
__global__ __launch_bounds__(256) void zgather_kernel(
        const int* __restrict__ rowptr, const int2* __restrict__ csr_sd,
        const float4* __restrict__ q_csr,
        const float* __restrict__ hprev,   // [N, FIN]
        float* __restrict__ z)             // [N, 4*FIN]
{
    int t = blockIdx.x * blockDim.x + threadIdx.x;
    int n = t / FIN;
    int f = t - n * FIN;
    if (n >= N_NODES) return;
    int beg = rowptr[n], end = rowptr[n + 1];
    float a0 = 0, a1 = 0, a2 = 0, a3 = 0;
    for (int k = beg; k < end; k++) {
        int s = csr_sd[k].x;             // broadcast within FIN-lane group
        float4 q = q_csr[k];             // broadcast
        float xv = hprev[(size_t)s * FIN + f];  // coalesced FIN-float segment
        a0 += q.x * xv; a1 += q.y * xv; a2 += q.z * xv; a3 += q.w * xv;
    }
    size_t base = (size_t)n * (4 * FIN) + f;
    z[base]           = a0;
    z[base + FIN]     = a1;
    z[base + 2 * FIN] = a2;
    z[base + 3 * FIN] = a3;
}

// ---------------- post: out[n,o] = relu( sum_k z[n,k]*Wp[k,o] + b[o] ),  k = h*FIN+f
// Tiled: thread = 4 nodes x 4 outputs (16 independent FMA chains).
// W pre-permuted into LDS k-major so the k-loop is linear; limited unroll
// + __launch_bounds__(256,4) keep VGPRs bounded (R4 full-unroll spilled).

template<int FIN, int FOUT>
__global__ __launch_bounds__(256, 4) void post_kernel(
        const float* __restrict__ z,    // [N, 4*FIN]
        const float* __restrict__ W,    // [FIN, 4*FOUT]
        const float* __restrict__ b,    // [FOUT]
        float* __restrict__ out)        // [N, FOUT]
{
    constexpr int K   = 4 * FIN;        // contraction length
    constexpr int OL  = FOUT / 4;       // o-lanes per node
    constexpr int NPB = 4 * (256 / OL); // nodes per block
    constexpr int WSZ = FIN * 4 * FOUT;
    __shared__ float Wp[WSZ];           // [K][FOUT], k = h*FIN+f
    for (int i = threadIdx.x; i < WSZ; i += 256) {
        int f = i / (4 * FOUT);
        int r = i - f * (4 * FOUT);
        int h = r / FOUT;
        int o = r - h * FOUT;
        Wp[(h * FIN + f) * FOUT + o] = W[i];
    }
    __syncthreads();

    int ol = threadIdx.x % OL;
    int g  = threadIdx.x / OL;
    int n0 = blockIdx.x * NPB + g * 4;

    float4 bv = *(const float4*)(b + 4 * ol);
    float4 acc[4];
    const float* zr[4];
    #pragma unroll
    for (int j = 0; j < 4; j++) {
        acc[j] = make_float4(0.f, 0.f, 0.f, 0.f);
        int nn = n0 + j; if (nn > N_NODES - 1) nn = N_NODES - 1;  // clamp for safe loads
        zr[j] = z + (size_t)nn * K;
    }

    #pragma unroll 2
    for (int kq = 0; kq < K / 4; kq++) {
        float4 zv[4];
        #pragma unroll
        for (int j = 0; j < 4; j++)
            zv[j] = *(const float4*)(zr[j] + 4 * kq);
        #pragma unroll
        for (int jj = 0; jj < 4; jj++) {
            float4 wv = *(const float4*)(Wp + (4 * kq + jj) * FOUT + 4 * ol);
            #pragma unroll
            for (int j = 0; j < 4; j++) {
                float s = (&zv[j].x)[jj];
                acc[j].x += s * wv.x;
                acc[j].y += s * wv.y;
                acc[j].z += s * wv.z;
                acc[j].w += s * wv.w;
            }
        }
    }

    #pragma unroll
    for (int j = 0; j < 4; j++) {
        int nn = n0 + j;
        if (nn < N_NODES) {
            float4 r;
            r.x = fmaxf(acc[j].x + bv.x, 0.0f);
            r.y = fmaxf(acc[j].y + bv.y, 0.0f);
            r.z = fmaxf(acc[j].z + bv.z, 0.0f);
            r.w = fmaxf(acc[j].w + bv.w, 0.0f);
            *(float4*)(out + (size_t)nn * FOUT + 4 * ol) = r;
        }
    }
}

// ---------------- fused linear tail: 64->32->16->8->4->1, relu..., sigmoid ----------------

__global__ __launch_bounds__(256) void tail_kernel(
        const float* __restrict__ h,   // [N, 64]
        const float* __restrict__ lw1, const float* __restrict__ lb1,
        const float* __restrict__ lw2, const float* __restrict__ lb2,
        const float* __restrict__ lw3, const float* __restrict__ lb3,
        const float* __restrict__ lw4, const float* __restrict__ lb4,
        const float* __restrict__ lw5, const float* __restrict__ lb5,
        float* __restrict__ out)
{
    __shared__ float w1[64 * 32], w2[32 * 16], w3[16 * 8], w4[8 * 4], w5[4];
    __shared__ float B1[32], B2[16], B3[8], B4[4], B5[1];
    for (int i = threadIdx.x; i < 64 * 32; i += blockDim.x) w1[i] = lw1[i];
    for (int i = threadIdx.x; i < 32 * 16; i += blockDim.x) w2[i] = lw2[i];
    for (int i = threadIdx.x; i < 16 * 8;  i += blockDim.x) w3[i] = lw3[i];
    for (int i = threadIdx.x; i < 8 * 4;   i += blockDim.x) w4[i] = lw4[i];
    for (int i = threadIdx.x; i < 4;       i += blockDim.x) w5[i] = lw5[i];
    for (int i = threadIdx.x; i < 32; i += blockDim.x) B1[i] = lb1[i];
    for (int i = threadIdx.x; i < 16; i += blockDim.x) B2[i] = lb2[i];
    for (int i = threadIdx.x; i < 8;  i += blockDim.x) B3[i] = lb3[i];
    for (int i = threadIdx.x; i < 4;  i += blockDim.x) B4[i] = lb4[i];
    if (threadIdx.x == 0) B5[0] = lb5[0];
    __syncthreads();

    int n = blockIdx.x * blockDim.x + threadIdx.x;
    if (n >= N_NODES) return;

    float a[64];
    #pragma unroll
    for (int i = 0; i < 64; i++) a[i] = h[(size_t)n * 64 + i];

    float t1[32];
    for (int o = 0; o < 32; o++) {
        float acc = B1[o];
        #pragma unroll
        for (int i = 0; i < 64; i++) acc += a[i] * w1[i * 32 + o];
        t1[o] = fmaxf(acc, 0.0f);
    }
    float t2[16];
    for (int o = 0; o < 16; o++) {
        float acc = B2[o];
        #pragma unroll
        for (int i = 0; i < 32; i++) acc += t1[i] * w2[i * 16 + o];
        t2[o] = fmaxf(acc, 0.0f);
    }
    float t3[8];
    for (int o = 0; o < 8; o++) {
        float acc = B3[o];
        #pragma unroll
        for (int i = 0; i < 16; i++) acc += t2[i] * w3[i * 8 + o];
        t3[o] = fmaxf(acc, 0.0f);
    }
    float t4[4];
    for (int o = 0; o < 4; o++) {
        float acc = B4[o];
        #pragma unroll
        for (int i = 0; i < 8; i++) acc += t3[i] * w4[i * 4 + o];
        t4[o] = fmaxf(acc, 0.0f);
    }
    float zf = B5[0];
    #pragma unroll
    for (int i = 0; i < 4; i++) zf += t4[i] * w5[i];
    out[n] = 1.0f / (1.0f + expf(-zf));
}

// ---------------- host launch ----------------

extern "C" void kernel_launch(void* const* d_in, const int* in_sizes, int n_in,
                              void* d_out, int out_size, void* d_ws, size_t ws_size,
                              hipStream_t stream) {
    const float* x   = (const float*)d_in[0];
    const int*   ei  = (const int*)d_in[1];
    const int*   src = ei;
    const int*   dst = ei + N_EDGES;
    const float* U1 = (const float*)d_in[2];  const float* c1 = (const float*)d_in[3];
    const float* W1 = (const float*)d_in[4];  const float* b1 = (const float*)d_in[5];
    const float* U2 = (const float*)d_in[6];  const float* c2 = (const float*)d_in[7];
    const float* W2 = (const float*)d_in[8];  const float* b2 = (const float*)d_in[9];
    const float* U3 = (const float*)d_in[10]; const float* c3 = (const float*)d_in[11];
    const float* W3 = (const float*)d_in[12]; const float* b3 = (const float*)d_in[13];
    const float* lw1 = (const float*)d_in[14]; const float* lb1 = (const float*)d_in[15];
    const float* lw2 = (const float*)d_in[16]; const float* lb2 = (const float*)d_in[17];
    const float* lw3 = (const float*)d_in[18]; const float* lb3 = (const float*)d_in[19];
    const float* lw4 = (const float*)d_in[20]; const float* lb4 = (const float*)d_in[21];
    const float* lw5 = (const float*)d_in[22]; const float* lb5 = (const float*)d_in[23];

    char* ws = (char*)d_ws;
    size_t off = 0;
    auto alloc = [&](size_t bytes) -> void* {
        void* ptr = (void*)(ws + off);
        off += (bytes + 255) & ~(size_t)255;
        return ptr;
    };
    int*    cnt       = (int*)alloc((size_t)N_NODES * 4);
    int*    rowptr    = (int*)alloc(((size_t)N_NODES + 1) * 4);
    int*    blockSums = (int*)alloc(512 * 4);
    int2*   csr_sd    = (int2*)alloc((size_t)N_EDGES * 8);
    float*  inv_deg   = (float*)alloc((size_t)N_NODES * 4);
    float*  p         = (float*)alloc((size_t)N_NODES * 4 * 4);    // [N,4]
    float4* q_csr     = (float4*)alloc((size_t)N_EDGES * 16);      // [E,4]
    float*  z         = (float*)alloc((size_t)N_NODES * 128 * 4);  // [N,128] max
    float*  h1        = (float*)alloc((size_t)N_NODES * 16 * 4);
    float*  h2        = (float*)alloc((size_t)N_NODES * 32 * 4);
    float*  h3        = (float*)alloc((size_t)N_NODES * 64 * 4);
    (void)ws_size;

    const int B = 256;
    int gN = (N_NODES + B - 1) / B;   // == NB
    int gE = (N_EDGES + B - 1) / B;

    // ---- build dst-CSR ----
    zero_int_kernel<<<gN, B, 0, stream>>>(cnt, N_NODES);
    hist_kernel<<<gE, B, 0, stream>>>(dst, cnt);
    scan_block_kernel<<<NB, 256, 0, stream>>>(cnt, rowptr, blockSums);
    scan_sums_kernel<<<1, 512, 0, stream>>>(blockSums);
    add_offsets_kernel<<<NB, 256, 0, stream>>>(rowptr, blockSums);
    scatter_kernel<<<gE, B, 0, stream>>>(src, dst, rowptr, cnt, csr_sd);
    invdeg_kernel<<<gN, B, 0, stream>>>(rowptr, inv_deg);

    // nodes-per-block for the tiled post kernels
    const int NPB1 = 4 * (256 / (16 / 4));   // 256
    const int NPB2 = 4 * (256 / (32 / 4));   // 128
    const int NPB3 = 4 * (256 / (64 / 4));   // 64

    // ---- conv1: 16 -> 16 ----
    p_kernel<16><<<gN, B, 0, stream>>>(x, U1, p);
    q_kernel<<<gE, B, 0, stream>>>(csr_sd, p, c1, inv_deg, q_csr);
    zgather_kernel<16><<<(N_NODES * 16 + B - 1) / B, B, 0, stream>>>(rowptr, csr_sd, q_csr, x, z);
    post_kernel<16, 16><<<(N_NODES + NPB1 - 1) / NPB1, B, 0, stream>>>(z, W1, b1, h1);

    // ---- conv2: 16 -> 32 ----
    p_kernel<16><<<gN, B, 0, stream>>>(h1, U2, p);
    q_kernel<<<gE, B, 0, stream>>>(csr_sd, p, c2, inv_deg, q_csr);
    zgather_kernel<16><<<(N_NODES * 16 + B - 1) / B, B, 0, stream>>>(rowptr, csr_sd, q_csr, h1, z);
    post_kernel<16, 32><<<(N_NODES + NPB2 - 1) / NPB2, B, 0, stream>>>(z, W2, b2, h2);

    // ---- conv3: 32 -> 64 ----
    p_kernel<32><<<gN, B, 0, stream>>>(h2, U3, p);
    q_kernel<<<gE, B, 0, stream>>>(csr_sd, p, c3, inv_deg, q_csr);
    zgather_kernel<32><<<(N_NODES * 32 + B - 1) / B, B, 0, stream>>>(rowptr, csr_sd, q_csr, h2, z);
    post_kernel<32, 64><<<(N_NODES + NPB3 - 1) / NPB3, B, 0, stream>>>(z, W3, b3, h3);

    // ---- tail MLP ----
    tail_kernel<<<gN, B, 0, stream>>>(h3, lw1, lb1, lw2, lb2, lw3, lb3,
                                      lw4, lb4, lw5, lb5, (float*)d_out);
}

// Round 7
// 559.982 us; speedup vs baseline: 2.3535x; 1.1247x over previous
//
#include <hip/hip_runtime.h>
#include <math.h>

#define N_NODES 100000
#define N_EDGES 1600000
#define HEADS 4
#define NB ((N_NODES + 255) / 256)   // 391 scan blocks

// ---------------- CSR build kernels ----------------

__global__ void zero_int_kernel(int* __restrict__ ptr, int n) {
    int i = blockIdx.x * blockDim.x + threadIdx.x;
    if (i < n) ptr[i] = 0;
}

__global__ void hist_kernel(const int* __restrict__ dst, int* __restrict__ cnt) {
    int e = blockIdx.x * blockDim.x + threadIdx.x;
    if (e < N_EDGES) atomicAdd(&cnt[dst[e]], 1);
}

// per-block exclusive scan of cnt -> rowptr (block-local), block totals -> blockSums
__global__ __launch_bounds__(256) void scan_block_kernel(
        const int* __restrict__ cnt, int* __restrict__ rowptr, int* __restrict__ blockSums) {
    __shared__ int tmp[256];
    int i = blockIdx.x * 256 + threadIdx.x;
    int v = (i < N_NODES) ? cnt[i] : 0;
    tmp[threadIdx.x] = v;
    __syncthreads();
    for (int off = 1; off < 256; off <<= 1) {
        int t = (threadIdx.x >= off) ? tmp[threadIdx.x - off] : 0;
        __syncthreads();
        tmp[threadIdx.x] += t;
        __syncthreads();
    }
    if (i < N_NODES) rowptr[i] = tmp[threadIdx.x] - v;        // exclusive, block-local
    if (threadIdx.x == 255) blockSums[blockIdx.x] = tmp[255]; // inclusive block total
}

// single-block exclusive scan of blockSums (NB=391 <= 512)
__global__ __launch_bounds__(512) void scan_sums_kernel(int* __restrict__ blockSums) {
    __shared__ int tmp[512];
    int i = threadIdx.x;
    int v = (i < NB) ? blockSums[i] : 0;
    tmp[i] = v;
    __syncthreads();
    for (int off = 1; off < 512; off <<= 1) {
        int t = (i >= off) ? tmp[i - off] : 0;
        __syncthreads();
        tmp[i] += t;
        __syncthreads();
    }
    if (i < NB) blockSums[i] = tmp[i] - v;                    // exclusive
}

__global__ __launch_bounds__(256) void add_offsets_kernel(
        int* __restrict__ rowptr, const int* __restrict__ blockSums) {
    int i = blockIdx.x * 256 + threadIdx.x;
    if (i < N_NODES) rowptr[i] += blockSums[blockIdx.x];
    if (i == 0) rowptr[N_NODES] = N_EDGES;
}

// cnt holds deg after hist; atomicSub makes it the scatter cursor (no re-zero).
// Only src stored (4 B/edge): one node bucket ~ deg*4B ~ one cache line.
__global__ void scatter_kernel(const int* __restrict__ src, const int* __restrict__ dst,
                               const int* __restrict__ rowptr, int* __restrict__ cnt,
                               int* __restrict__ csr_src) {
    int e = blockIdx.x * blockDim.x + threadIdx.x;
    if (e >= N_EDGES) return;
    int d = dst[e];
    int old = atomicSub(&cnt[d], 1);
    csr_src[rowptr[d] + old - 1] = src[e];
}

// ---------------- p = h @ U  [N,4] ----------------

template<int FIN>
__global__ __launch_bounds__(256) void p_kernel(
        const float* __restrict__ h, const float* __restrict__ U,  // [FIN,4]
        float* __restrict__ p)                                     // [N,4]
{
    int n = blockIdx.x * blockDim.x + threadIdx.x;
    if (n >= N_NODES) return;
    float a0 = 0, a1 = 0, a2 = 0, a3 = 0;
    const float* hr = h + (size_t)n * FIN;
    #pragma unroll
    for (int f = 0; f < FIN; f++) {
        float xv = hr[f];
        a0 += xv * U[f * 4 + 0];
        a1 += xv * U[f * 4 + 1];
        a2 += xv * U[f * 4 + 2];
        a3 += xv * U[f * 4 + 3];
    }
    *(float4*)(p + (size_t)n * 4) = make_float4(a0, a1, a2, a3);
}

// ---------------- fused zgather: per block = NPB nodes' contiguous CSR range.
// Phase 1: block threads compute q (softmax/deg) for the range into LDS
//          (dst via binary search over block rowptr; deg from same).
// Phase 2: per-(node,f) gather accumulates z from LDS q + hprev rows.

template<int FIN>
__global__ __launch_bounds__(256) void zgather_kernel(
        const int* __restrict__ rowptr, const int* __restrict__ csr_src,
        const float* __restrict__ p,     // [N,4]
        const float* __restrict__ cvec,  // [4]
        const float* __restrict__ hprev, // [N, FIN]
        float* __restrict__ z)           // [N, 4*FIN]
{
    constexpr int NPB   = 256 / FIN;    // nodes per block
    constexpr int CHUNK = 1024;         // edges per LDS pass (typical block range ~ NPB*16)
    __shared__ int    sbeg[NPB + 1];
    __shared__ float4 qs[CHUNK];
    __shared__ int    ssrc[CHUNK];

    int tid  = threadIdx.x;
    int nloc = tid / FIN;
    int f    = tid - nloc * FIN;
    int n0   = blockIdx.x * NPB;
    int n    = n0 + nloc;

    if (tid <= NPB) {
        int idx = n0 + tid;
        sbeg[tid] = rowptr[idx > N_NODES ? N_NODES : idx];
    }
    float c0 = cvec[0], c1 = cvec[1], c2 = cvec[2], c3 = cvec[3];
    __syncthreads();

    int BB = sbeg[0], BE = sbeg[NPB];
    int beg = sbeg[nloc], end = sbeg[nloc + 1];   // for n>=N_NODES: beg==end==E

    float a0 = 0, a1 = 0, a2 = 0, a3 = 0;

    for (int cbase = BB; cbase < BE; cbase += CHUNK) {
        int cend = min(cbase + CHUNK, BE);
        __syncthreads();   // previous pass's LDS reads done
        // phase 1: q for edges [cbase, cend)
        for (int k = cbase + tid; k < cend; k += 256) {
            int s = csr_src[k];
            int lo = 0, hi = NPB;                 // invariant: sbeg[lo] <= k < sbeg[hi]
            while (hi - lo > 1) { int mid = (lo + hi) >> 1; if (k < sbeg[mid]) hi = mid; else lo = mid; }
            float4 ps = *(const float4*)(p + (size_t)s * 4);
            float4 pd = *(const float4*)(p + (size_t)(n0 + lo) * 4);
            float l0 = ps.x - pd.x + c0;
            float l1 = ps.y - pd.y + c1;
            float l2 = ps.z - pd.z + c2;
            float l3 = ps.w - pd.w + c3;
            float m  = fmaxf(fmaxf(l0, l1), fmaxf(l2, l3));
            float e0 = __expf(l0 - m), e1 = __expf(l1 - m);
            float e2 = __expf(l2 - m), e3 = __expf(l3 - m);
            float deg = (float)(sbeg[lo + 1] - sbeg[lo]);
            float inv = 1.0f / (fmaxf(deg, 1.0f) * (e0 + e1 + e2 + e3));
            qs[k - cbase]   = make_float4(e0 * inv, e1 * inv, e2 * inv, e3 * inv);
            ssrc[k - cbase] = s;
        }
        __syncthreads();
        // phase 2: gather my node's slice of this chunk
        int kb = beg > cbase ? beg : cbase;
        int ke = end < cend ? end : cend;
        for (int k = kb; k < ke; k++) {
            int s    = ssrc[k - cbase];           // broadcast within FIN-lane group
            float4 q = qs[k - cbase];             // broadcast
            float xv = hprev[(size_t)s * FIN + f];// coalesced FIN-float segment
            a0 += q.x * xv; a1 += q.y * xv; a2 += q.z * xv; a3 += q.w * xv;
        }
    }

    if (n < N_NODES) {
        size_t base = (size_t)n * (4 * FIN) + f;
        z[base]           = a0;
        z[base + FIN]     = a1;
        z[base + 2 * FIN] = a2;
        z[base + 3 * FIN] = a3;
    }
}

// ---------------- post: out[n,o] = relu( sum_k z[n,k]*Wp[k,o] + b[o] ),  k = h*FIN+f
// Tiled: thread = 4 nodes x 4 outputs (16 independent FMA chains).
// W pre-permuted into LDS k-major; limited unroll + __launch_bounds__(256,4)
// keep VGPRs bounded (R4 full-unroll spilled).

template<int FIN, int FOUT>
__global__ __launch_bounds__(256, 4) void post_kernel(
        const float* __restrict__ z,    // [N, 4*FIN]
        const float* __restrict__ W,    // [FIN, 4*FOUT]
        const float* __restrict__ b,    // [FOUT]
        float* __restrict__ out)        // [N, FOUT]
{
    constexpr int K   = 4 * FIN;        // contraction length
    constexpr int OL  = FOUT / 4;       // o-lanes per node
    constexpr int NPB = 4 * (256 / OL); // nodes per block
    constexpr int WSZ = FIN * 4 * FOUT;
    __shared__ float Wp[WSZ];           // [K][FOUT], k = h*FIN+f
    for (int i = threadIdx.x; i < WSZ; i += 256) {
        int f = i / (4 * FOUT);
        int r = i - f * (4 * FOUT);
        int h = r / FOUT;
        int o = r - h * FOUT;
        Wp[(h * FIN + f) * FOUT + o] = W[i];
    }
    __syncthreads();

    int ol = threadIdx.x % OL;
    int g  = threadIdx.x / OL;
    int n0 = blockIdx.x * NPB + g * 4;

    float4 bv = *(const float4*)(b + 4 * ol);
    float4 acc[4];
    const float* zr[4];
    #pragma unroll
    for (int j = 0; j < 4; j++) {
        acc[j] = make_float4(0.f, 0.f, 0.f, 0.f);
        int nn = n0 + j; if (nn > N_NODES - 1) nn = N_NODES - 1;  // clamp for safe loads
        zr[j] = z + (size_t)nn * K;
    }

    #pragma unroll 2
    for (int kq = 0; kq < K / 4; kq++) {
        float4 zv[4];
        #pragma unroll
        for (int j = 0; j < 4; j++)
            zv[j] = *(const float4*)(zr[j] + 4 * kq);
        #pragma unroll
        for (int jj = 0; jj < 4; jj++) {
            float4 wv = *(const float4*)(Wp + (4 * kq + jj) * FOUT + 4 * ol);
            #pragma unroll
            for (int j = 0; j < 4; j++) {
                float s = (&zv[j].x)[jj];
                acc[j].x += s * wv.x;
                acc[j].y += s * wv.y;
                acc[j].z += s * wv.z;
                acc[j].w += s * wv.w;
            }
        }
    }

    #pragma unroll
    for (int j = 0; j < 4; j++) {
        int nn = n0 + j;
        if (nn < N_NODES) {
            float4 r;
            r.x = fmaxf(acc[j].x + bv.x, 0.0f);
            r.y = fmaxf(acc[j].y + bv.y, 0.0f);
            r.z = fmaxf(acc[j].z + bv.z, 0.0f);
            r.w = fmaxf(acc[j].w + bv.w, 0.0f);
            *(float4*)(out + (size_t)nn * FOUT + 4 * ol) = r;
        }
    }
}

// ---------------- fused linear tail: 64->32->16->8->4->1, relu..., sigmoid ----------------

__global__ __launch_bounds__(256) void tail_kernel(
        const float* __restrict__ h,   // [N, 64]
        const float* __restrict__ lw1, const float* __restrict__ lb1,
        const float* __restrict__ lw2, const float* __restrict__ lb2,
        const float* __restrict__ lw3, const float* __restrict__ lb3,
        const float* __restrict__ lw4, const float* __restrict__ lb4,
        const float* __restrict__ lw5, const float* __restrict__ lb5,
        float* __restrict__ out)
{
    __shared__ float w1[64 * 32], w2[32 * 16], w3[16 * 8], w4[8 * 4], w5[4];
    __shared__ float B1[32], B2[16], B3[8], B4[4], B5[1];
    for (int i = threadIdx.x; i < 64 * 32; i += blockDim.x) w1[i] = lw1[i];
    for (int i = threadIdx.x; i < 32 * 16; i += blockDim.x) w2[i] = lw2[i];
    for (int i = threadIdx.x; i < 16 * 8;  i += blockDim.x) w3[i] = lw3[i];
    for (int i = threadIdx.x; i < 8 * 4;   i += blockDim.x) w4[i] = lw4[i];
    for (int i = threadIdx.x; i < 4;       i += blockDim.x) w5[i] = lw5[i];
    for (int i = threadIdx.x; i < 32; i += blockDim.x) B1[i] = lb1[i];
    for (int i = threadIdx.x; i < 16; i += blockDim.x) B2[i] = lb2[i];
    for (int i = threadIdx.x; i < 8;  i += blockDim.x) B3[i] = lb3[i];
    for (int i = threadIdx.x; i < 4;  i += blockDim.x) B4[i] = lb4[i];
    if (threadIdx.x == 0) B5[0] = lb5[0];
    __syncthreads();

    int n = blockIdx.x * blockDim.x + threadIdx.x;
    if (n >= N_NODES) return;

    float a[64];
    #pragma unroll
    for (int i = 0; i < 64; i++) a[i] = h[(size_t)n * 64 + i];

    float t1[32];
    for (int o = 0; o < 32; o++) {
        float acc = B1[o];
        #pragma unroll
        for (int i = 0; i < 64; i++) acc += a[i] * w1[i * 32 + o];
        t1[o] = fmaxf(acc, 0.0f);
    }
    float t2[16];
    for (int o = 0; o < 16; o++) {
        float acc = B2[o];
        #pragma unroll
        for (int i = 0; i < 32; i++) acc += t1[i] * w2[i * 16 + o];
        t2[o] = fmaxf(acc, 0.0f);
    }
    float t3[8];
    for (int o = 0; o < 8; o++) {
        float acc = B3[o];
        #pragma unroll
        for (int i = 0; i < 16; i++) acc += t2[i] * w3[i * 8 + o];
        t3[o] = fmaxf(acc, 0.0f);
    }
    float t4[4];
    for (int o = 0; o < 4; o++) {
        float acc = B4[o];
        #pragma unroll
        for (int i = 0; i < 8; i++) acc += t3[i] * w4[i * 4 + o];
        t4[o] = fmaxf(acc, 0.0f);
    }
    float zf = B5[0];
    #pragma unroll
    for (int i = 0; i < 4; i++) zf += t4[i] * w5[i];
    out[n] = 1.0f / (1.0f + expf(-zf));
}

// ---------------- host launch ----------------

extern "C" void kernel_launch(void* const* d_in, const int* in_sizes, int n_in,
                              void* d_out, int out_size, void* d_ws, size_t ws_size,
                              hipStream_t stream) {
    const float* x   = (const float*)d_in[0];
    const int*   ei  = (const int*)d_in[1];
    const int*   src = ei;
    const int*   dst = ei + N_EDGES;
    const float* U1 = (const float*)d_in[2];  const float* c1 = (const float*)d_in[3];
    const float* W1 = (const float*)d_in[4];  const float* b1 = (const float*)d_in[5];
    const float* U2 = (const float*)d_in[6];  const float* c2 = (const float*)d_in[7];
    const float* W2 = (const float*)d_in[8];  const float* b2 = (const float*)d_in[9];
    const float* U3 = (const float*)d_in[10]; const float* c3 = (const float*)d_in[11];
    const float* W3 = (const float*)d_in[12]; const float* b3 = (const float*)d_in[13];
    const float* lw1 = (const float*)d_in[14]; const float* lb1 = (const float*)d_in[15];
    const float* lw2 = (const float*)d_in[16]; const float* lb2 = (const float*)d_in[17];
    const float* lw3 = (const float*)d_in[18]; const float* lb3 = (const float*)d_in[19];
    const float* lw4 = (const float*)d_in[20]; const float* lb4 = (const float*)d_in[21];
    const float* lw5 = (const float*)d_in[22]; const float* lb5 = (const float*)d_in[23];

    char* ws = (char*)d_ws;
    size_t off = 0;
    auto alloc = [&](size_t bytes) -> void* {
        void* ptr = (void*)(ws + off);
        off += (bytes + 255) & ~(size_t)255;
        return ptr;
    };
    int*    cnt       = (int*)alloc((size_t)N_NODES * 4);
    int*    rowptr    = (int*)alloc(((size_t)N_NODES + 1) * 4);
    int*    blockSums = (int*)alloc(512 * 4);
    int*    csr_src   = (int*)alloc((size_t)N_EDGES * 4);
    float*  p         = (float*)alloc((size_t)N_NODES * 4 * 4);    // [N,4]
    float*  z         = (float*)alloc((size_t)N_NODES * 128 * 4);  // [N,128] max
    float*  h1        = (float*)alloc((size_t)N_NODES * 16 * 4);
    float*  h2        = (float*)alloc((size_t)N_NODES * 32 * 4);
    float*  h3        = (float*)alloc((size_t)N_NODES * 64 * 4);
    (void)ws_size;

    const int B = 256;
    int gN = (N_NODES + B - 1) / B;   // == NB
    int gE = (N_EDGES + B - 1) / B;

    // ---- build dst-CSR ----
    zero_int_kernel<<<gN, B, 0, stream>>>(cnt, N_NODES);
    hist_kernel<<<gE, B, 0, stream>>>(dst, cnt);
    scan_block_kernel<<<NB, 256, 0, stream>>>(cnt, rowptr, blockSums);
    scan_sums_kernel<<<1, 512, 0, stream>>>(blockSums);
    add_offsets_kernel<<<NB, 256, 0, stream>>>(rowptr, blockSums);
    scatter_kernel<<<gE, B, 0, stream>>>(src, dst, rowptr, cnt, csr_src);

    // zgather grids: block covers 256/FIN nodes
    const int ZG16 = (N_NODES + (256 / 16) - 1) / (256 / 16);   // 6250
    const int ZG32 = (N_NODES + (256 / 32) - 1) / (256 / 32);   // 12500
    // post grids
    const int NPB1 = 4 * (256 / (16 / 4));   // 256
    const int NPB2 = 4 * (256 / (32 / 4));   // 128
    const int NPB3 = 4 * (256 / (64 / 4));   // 64

    // ---- conv1: 16 -> 16 ----
    p_kernel<16><<<gN, B, 0, stream>>>(x, U1, p);
    zgather_kernel<16><<<ZG16, B, 0, stream>>>(rowptr, csr_src, p, c1, x, z);
    post_kernel<16, 16><<<(N_NODES + NPB1 - 1) / NPB1, B, 0, stream>>>(z, W1, b1, h1);

    // ---- conv2: 16 -> 32 ----
    p_kernel<16><<<gN, B, 0, stream>>>(h1, U2, p);
    zgather_kernel<16><<<ZG16, B, 0, stream>>>(rowptr, csr_src, p, c2, h1, z);
    post_kernel<16, 32><<<(N_NODES + NPB2 - 1) / NPB2, B, 0, stream>>>(z, W2, b2, h2);

    // ---- conv3: 32 -> 64 ----
    p_kernel<32><<<gN, B, 0, stream>>>(h2, U3, p);
    zgather_kernel<32><<<ZG32, B, 0, stream>>>(rowptr, csr_src, p, c3, h2, z);
    post_kernel<32, 64><<<(N_NODES + NPB3 - 1) / NPB3, B, 0, stream>>>(z, W3, b3, h3);

    // ---- tail MLP ----
    tail_kernel<<<gN, B, 0, stream>>>(h3, lw1, lb1, lw2, lb2, lw3, lb3,
                                      lw4, lb4, lw5, lb5, (float*)d_out);
}

// Round 8
// 423.619 us; speedup vs baseline: 3.1110x; 1.3219x over previous
//
#include <hip/hip_runtime.h>
#include <math.h>

#define N_NODES 100000
#define N_EDGES 1600000
#define HEADS 4
#define NBKT ((N_NODES + 255) / 256)        // 391 coarse buckets (256 nodes each)
#define CHUNK_E 4096
#define NCHUNK ((N_EDGES + CHUNK_E - 1) / CHUNK_E)  // 391 edge chunks

// ---------------- CSR build: two-level multisplit ----------------

__global__ void zero_int_kernel(int* __restrict__ ptr, int n) {
    int i = blockIdx.x * blockDim.x + threadIdx.x;
    if (i < n) ptr[i] = 0;
}

// K1: coarse histogram via LDS (one global atomic per (block,bucket))
__global__ __launch_bounds__(256) void bhist_kernel(const int* __restrict__ dst,
                                                    int* __restrict__ bucket_cnt) {
    __shared__ int h[NBKT];
    for (int i = threadIdx.x; i < NBKT; i += 256) h[i] = 0;
    __syncthreads();
    int base = blockIdx.x * CHUNK_E;
    #pragma unroll
    for (int j = 0; j < CHUNK_E / 256; j++) {
        int e = base + j * 256 + threadIdx.x;
        if (e < N_EDGES) atomicAdd(&h[dst[e] >> 8], 1);
    }
    __syncthreads();
    for (int i = threadIdx.x; i < NBKT; i += 256)
        if (h[i]) atomicAdd(&bucket_cnt[i], h[i]);
}

// K2: single-block exclusive scan of bucket counts -> base + cursor
__global__ __launch_bounds__(512) void bscan_kernel(const int* __restrict__ bucket_cnt,
                                                    int* __restrict__ bucket_base,
                                                    int* __restrict__ bucket_cursor) {
    __shared__ int tmp[512];
    int i = threadIdx.x;
    int v = (i < NBKT) ? bucket_cnt[i] : 0;
    tmp[i] = v;
    __syncthreads();
    for (int off = 1; off < 512; off <<= 1) {
        int t = (i >= off) ? tmp[i - off] : 0;
        __syncthreads();
        tmp[i] += t;
        __syncthreads();
    }
    int excl = tmp[i] - v;
    if (i < NBKT) { bucket_base[i] = excl; bucket_cursor[i] = excl; }
    if (i == NBKT) bucket_base[NBKT] = N_EDGES;
}

// K3: partition edges into coarse-bucket regions; packed = (dst&255)<<20 | src.
// Per-block: LDS hist -> one cursor atomic per bucket -> clustered writes
// (~10 consecutive slots per bucket per block => line-level clustering in L2).
__global__ __launch_bounds__(256) void partition_kernel(const int* __restrict__ src,
                                                        const int* __restrict__ dst,
                                                        int* __restrict__ bucket_cursor,
                                                        int* __restrict__ csr_tmp) {
    constexpr int EPT = CHUNK_E / 256;   // 16 edges per thread
    __shared__ int h[NBKT];
    __shared__ int gbase[NBKT];
    __shared__ int rcnt[NBKT];
    for (int i = threadIdx.x; i < NBKT; i += 256) { h[i] = 0; rcnt[i] = 0; }
    __syncthreads();
    int base = blockIdx.x * CHUNK_E;
    int d[EPT], s[EPT];
    #pragma unroll
    for (int j = 0; j < EPT; j++) {
        int e = base + j * 256 + threadIdx.x;
        d[j] = (e < N_EDGES) ? dst[e] : -1;
        s[j] = (e < N_EDGES) ? src[e] : 0;
        if (d[j] >= 0) atomicAdd(&h[d[j] >> 8], 1);
    }
    __syncthreads();
    for (int i = threadIdx.x; i < NBKT; i += 256)
        if (h[i]) gbase[i] = atomicAdd(&bucket_cursor[i], h[i]);
    __syncthreads();
    #pragma unroll
    for (int j = 0; j < EPT; j++) {
        if (d[j] >= 0) {
            int b = d[j] >> 8;
            int r = atomicAdd(&rcnt[b], 1);
            csr_tmp[gbase[b] + r] = ((d[j] & 255) << 20) | s[j];
        }
    }
}

// K4: per-bucket (256 nodes): per-node count+scan in LDS -> rowptr;
// sort bucket edges into LDS stage; coalesced copy-out to csr_src.
__global__ __launch_bounds__(256) void bucket_build_kernel(const int* __restrict__ bucket_base,
                                                           const int* __restrict__ csr_tmp,
                                                           int* __restrict__ rowptr,
                                                           int* __restrict__ csr_src) {
    __shared__ int cnt[256];
    __shared__ int tscan[256];
    __shared__ int exc[256];
    __shared__ int stage[8192];
    int b = blockIdx.x;
    int rbeg = bucket_base[b], rend = bucket_base[b + 1];
    int sz = rend - rbeg;
    int tid = threadIdx.x;

    cnt[tid] = 0;
    __syncthreads();
    for (int k = rbeg + tid; k < rend; k += 256) atomicAdd(&cnt[csr_tmp[k] >> 20], 1);
    __syncthreads();
    int v = cnt[tid];
    tscan[tid] = v;
    __syncthreads();
    for (int off = 1; off < 256; off <<= 1) {
        int t = (tid >= off) ? tscan[tid - off] : 0;
        __syncthreads();
        tscan[tid] += t;
        __syncthreads();
    }
    int ex = tscan[tid] - v;
    int node = b * 256 + tid;
    if (node < N_NODES) rowptr[node] = rbeg + ex;
    if (b == 0 && tid == 0) rowptr[N_NODES] = N_EDGES;
    exc[tid] = ex;
    cnt[tid] = 0;
    __syncthreads();

    if (sz <= 8192) {
        for (int k = rbeg + tid; k < rend; k += 256) {
            int pk = csr_tmp[k];
            int dl = pk >> 20;
            int r  = atomicAdd(&cnt[dl], 1);
            stage[exc[dl] + r] = pk & ((1 << 20) - 1);
        }
        __syncthreads();
        for (int i = tid; i < sz; i += 256) csr_src[rbeg + i] = stage[i];
    } else {   // safety fallback (bucket bigger than stage)
        for (int k = rbeg + tid; k < rend; k += 256) {
            int pk = csr_tmp[k];
            int dl = pk >> 20;
            int r  = atomicAdd(&cnt[dl], 1);
            csr_src[rbeg + exc[dl] + r] = pk & ((1 << 20) - 1);
        }
    }
}

// ---------------- p = h @ U  [N,4] ----------------

template<int FIN>
__global__ __launch_bounds__(256) void p_kernel(
        const float* __restrict__ h, const float* __restrict__ U,  // [FIN,4]
        float* __restrict__ p)                                     // [N,4]
{
    int n = blockIdx.x * blockDim.x + threadIdx.x;
    if (n >= N_NODES) return;
    float a0 = 0, a1 = 0, a2 = 0, a3 = 0;
    const float* hr = h + (size_t)n * FIN;
    #pragma unroll
    for (int f = 0; f < FIN; f++) {
        float xv = hr[f];
        a0 += xv * U[f * 4 + 0];
        a1 += xv * U[f * 4 + 1];
        a2 += xv * U[f * 4 + 2];
        a3 += xv * U[f * 4 + 3];
    }
    *(float4*)(p + (size_t)n * 4) = make_float4(a0, a1, a2, a3);
}

// ---------------- fused zgather: per block = NPB nodes' contiguous CSR range.
// Phase 1: block threads compute q (softmax/deg) for the range into LDS
//          (dst via binary search over block rowptr; deg from same).
// Phase 2: per-(node,f) gather accumulates z from LDS q + hprev rows.

template<int FIN>
__global__ __launch_bounds__(256) void zgather_kernel(
        const int* __restrict__ rowptr, const int* __restrict__ csr_src,
        const float* __restrict__ p,     // [N,4]
        const float* __restrict__ cvec,  // [4]
        const float* __restrict__ hprev, // [N, FIN]
        float* __restrict__ z)           // [N, 4*FIN]
{
    constexpr int NPB   = 256 / FIN;    // nodes per block
    constexpr int CHUNK = 1024;         // edges per LDS pass
    __shared__ int    sbeg[NPB + 1];
    __shared__ float4 qs[CHUNK];
    __shared__ int    ssrc[CHUNK];

    int tid  = threadIdx.x;
    int nloc = tid / FIN;
    int f    = tid - nloc * FIN;
    int n0   = blockIdx.x * NPB;
    int n    = n0 + nloc;

    if (tid <= NPB) {
        int idx = n0 + tid;
        sbeg[tid] = rowptr[idx > N_NODES ? N_NODES : idx];
    }
    float c0 = cvec[0], c1 = cvec[1], c2 = cvec[2], c3 = cvec[3];
    __syncthreads();

    int BB = sbeg[0], BE = sbeg[NPB];
    int beg = sbeg[nloc], end = sbeg[nloc + 1];

    float a0 = 0, a1 = 0, a2 = 0, a3 = 0;

    for (int cbase = BB; cbase < BE; cbase += CHUNK) {
        int cend = min(cbase + CHUNK, BE);
        __syncthreads();
        for (int k = cbase + tid; k < cend; k += 256) {
            int s = csr_src[k];
            int lo = 0, hi = NPB;
            while (hi - lo > 1) { int mid = (lo + hi) >> 1; if (k < sbeg[mid]) hi = mid; else lo = mid; }
            float4 ps = *(const float4*)(p + (size_t)s * 4);
            float4 pd = *(const float4*)(p + (size_t)(n0 + lo) * 4);
            float l0 = ps.x - pd.x + c0;
            float l1 = ps.y - pd.y + c1;
            float l2 = ps.z - pd.z + c2;
            float l3 = ps.w - pd.w + c3;
            float m  = fmaxf(fmaxf(l0, l1), fmaxf(l2, l3));
            float e0 = __expf(l0 - m), e1 = __expf(l1 - m);
            float e2 = __expf(l2 - m), e3 = __expf(l3 - m);
            float deg = (float)(sbeg[lo + 1] - sbeg[lo]);
            float inv = 1.0f / (fmaxf(deg, 1.0f) * (e0 + e1 + e2 + e3));
            qs[k - cbase]   = make_float4(e0 * inv, e1 * inv, e2 * inv, e3 * inv);
            ssrc[k - cbase] = s;
        }
        __syncthreads();
        int kb = beg > cbase ? beg : cbase;
        int ke = end < cend ? end : cend;
        for (int k = kb; k < ke; k++) {
            int s    = ssrc[k - cbase];
            float4 q = qs[k - cbase];
            float xv = hprev[(size_t)s * FIN + f];
            a0 += q.x * xv; a1 += q.y * xv; a2 += q.z * xv; a3 += q.w * xv;
        }
    }

    if (n < N_NODES) {
        size_t base = (size_t)n * (4 * FIN) + f;
        z[base]           = a0;
        z[base + FIN]     = a1;
        z[base + 2 * FIN] = a2;
        z[base + 3 * FIN] = a3;
    }
}

// ---------------- post: out[n,o] = relu( sum_k z[n,k]*Wp[k,o] + b[o] ),  k = h*FIN+f

template<int FIN, int FOUT>
__global__ __launch_bounds__(256, 4) void post_kernel(
        const float* __restrict__ z,    // [N, 4*FIN]
        const float* __restrict__ W,    // [FIN, 4*FOUT]
        const float* __restrict__ b,    // [FOUT]
        float* __restrict__ out)        // [N, FOUT]
{
    constexpr int K   = 4 * FIN;
    constexpr int OL  = FOUT / 4;
    constexpr int NPB = 4 * (256 / OL);
    constexpr int WSZ = FIN * 4 * FOUT;
    __shared__ float Wp[WSZ];           // [K][FOUT], k = h*FIN+f
    for (int i = threadIdx.x; i < WSZ; i += 256) {
        int f = i / (4 * FOUT);
        int r = i - f * (4 * FOUT);
        int h = r / FOUT;
        int o = r - h * FOUT;
        Wp[(h * FIN + f) * FOUT + o] = W[i];
    }
    __syncthreads();

    int ol = threadIdx.x % OL;
    int g  = threadIdx.x / OL;
    int n0 = blockIdx.x * NPB + g * 4;

    float4 bv = *(const float4*)(b + 4 * ol);
    float4 acc[4];
    const float* zr[4];
    #pragma unroll
    for (int j = 0; j < 4; j++) {
        acc[j] = make_float4(0.f, 0.f, 0.f, 0.f);
        int nn = n0 + j; if (nn > N_NODES - 1) nn = N_NODES - 1;
        zr[j] = z + (size_t)nn * K;
    }

    #pragma unroll 2
    for (int kq = 0; kq < K / 4; kq++) {
        float4 zv[4];
        #pragma unroll
        for (int j = 0; j < 4; j++)
            zv[j] = *(const float4*)(zr[j] + 4 * kq);
        #pragma unroll
        for (int jj = 0; jj < 4; jj++) {
            float4 wv = *(const float4*)(Wp + (4 * kq + jj) * FOUT + 4 * ol);
            #pragma unroll
            for (int j = 0; j < 4; j++) {
                float s = (&zv[j].x)[jj];
                acc[j].x += s * wv.x;
                acc[j].y += s * wv.y;
                acc[j].z += s * wv.z;
                acc[j].w += s * wv.w;
            }
        }
    }

    #pragma unroll
    for (int j = 0; j < 4; j++) {
        int nn = n0 + j;
        if (nn < N_NODES) {
            float4 r;
            r.x = fmaxf(acc[j].x + bv.x, 0.0f);
            r.y = fmaxf(acc[j].y + bv.y, 0.0f);
            r.z = fmaxf(acc[j].z + bv.z, 0.0f);
            r.w = fmaxf(acc[j].w + bv.w, 0.0f);
            *(float4*)(out + (size_t)nn * FOUT + 4 * ol) = r;
        }
    }
}

// ---------------- fused linear tail: 64->32->16->8->4->1, relu..., sigmoid ----------------

__global__ __launch_bounds__(256) void tail_kernel(
        const float* __restrict__ h,   // [N, 64]
        const float* __restrict__ lw1, const float* __restrict__ lb1,
        const float* __restrict__ lw2, const float* __restrict__ lb2,
        const float* __restrict__ lw3, const float* __restrict__ lb3,
        const float* __restrict__ lw4, const float* __restrict__ lb4,
        const float* __restrict__ lw5, const float* __restrict__ lb5,
        float* __restrict__ out)
{
    __shared__ float w1[64 * 32], w2[32 * 16], w3[16 * 8], w4[8 * 4], w5[4];
    __shared__ float B1[32], B2[16], B3[8], B4[4], B5[1];
    for (int i = threadIdx.x; i < 64 * 32; i += blockDim.x) w1[i] = lw1[i];
    for (int i = threadIdx.x; i < 32 * 16; i += blockDim.x) w2[i] = lw2[i];
    for (int i = threadIdx.x; i < 16 * 8;  i += blockDim.x) w3[i] = lw3[i];
    for (int i = threadIdx.x; i < 8 * 4;   i += blockDim.x) w4[i] = lw4[i];
    for (int i = threadIdx.x; i < 4;       i += blockDim.x) w5[i] = lw5[i];
    for (int i = threadIdx.x; i < 32; i += blockDim.x) B1[i] = lb1[i];
    for (int i = threadIdx.x; i < 16; i += blockDim.x) B2[i] = lb2[i];
    for (int i = threadIdx.x; i < 8;  i += blockDim.x) B3[i] = lb3[i];
    for (int i = threadIdx.x; i < 4;  i += blockDim.x) B4[i] = lb4[i];
    if (threadIdx.x == 0) B5[0] = lb5[0];
    __syncthreads();

    int n = blockIdx.x * blockDim.x + threadIdx.x;
    if (n >= N_NODES) return;

    float a[64];
    #pragma unroll
    for (int i = 0; i < 64; i++) a[i] = h[(size_t)n * 64 + i];

    float t1[32];
    for (int o = 0; o < 32; o++) {
        float acc = B1[o];
        #pragma unroll
        for (int i = 0; i < 64; i++) acc += a[i] * w1[i * 32 + o];
        t1[o] = fmaxf(acc, 0.0f);
    }
    float t2[16];
    for (int o = 0; o < 16; o++) {
        float acc = B2[o];
        #pragma unroll
        for (int i = 0; i < 32; i++) acc += t1[i] * w2[i * 16 + o];
        t2[o] = fmaxf(acc, 0.0f);
    }
    float t3[8];
    for (int o = 0; o < 8; o++) {
        float acc = B3[o];
        #pragma unroll
        for (int i = 0; i < 16; i++) acc += t2[i] * w3[i * 8 + o];
        t3[o] = fmaxf(acc, 0.0f);
    }
    float t4[4];
    for (int o = 0; o < 4; o++) {
        float acc = B4[o];
        #pragma unroll
        for (int i = 0; i < 8; i++) acc += t3[i] * w4[i * 4 + o];
        t4[o] = fmaxf(acc, 0.0f);
    }
    float zf = B5[0];
    #pragma unroll
    for (int i = 0; i < 4; i++) zf += t4[i] * w5[i];
    out[n] = 1.0f / (1.0f + expf(-zf));
}

// ---------------- host launch ----------------

extern "C" void kernel_launch(void* const* d_in, const int* in_sizes, int n_in,
                              void* d_out, int out_size, void* d_ws, size_t ws_size,
                              hipStream_t stream) {
    const float* x   = (const float*)d_in[0];
    const int*   ei  = (const int*)d_in[1];
    const int*   src = ei;
    const int*   dst = ei + N_EDGES;
    const float* U1 = (const float*)d_in[2];  const float* c1 = (const float*)d_in[3];
    const float* W1 = (const float*)d_in[4];  const float* b1 = (const float*)d_in[5];
    const float* U2 = (const float*)d_in[6];  const float* c2 = (const float*)d_in[7];
    const float* W2 = (const float*)d_in[8];  const float* b2 = (const float*)d_in[9];
    const float* U3 = (const float*)d_in[10]; const float* c3 = (const float*)d_in[11];
    const float* W3 = (const float*)d_in[12]; const float* b3 = (const float*)d_in[13];
    const float* lw1 = (const float*)d_in[14]; const float* lb1 = (const float*)d_in[15];
    const float* lw2 = (const float*)d_in[16]; const float* lb2 = (const float*)d_in[17];
    const float* lw3 = (const float*)d_in[18]; const float* lb3 = (const float*)d_in[19];
    const float* lw4 = (const float*)d_in[20]; const float* lb4 = (const float*)d_in[21];
    const float* lw5 = (const float*)d_in[22]; const float* lb5 = (const float*)d_in[23];

    char* ws = (char*)d_ws;
    size_t off = 0;
    auto alloc = [&](size_t bytes) -> void* {
        void* ptr = (void*)(ws + off);
        off += (bytes + 255) & ~(size_t)255;
        return ptr;
    };
    int*    bucket_cnt    = (int*)alloc((size_t)(NBKT + 1) * 4);
    int*    bucket_base   = (int*)alloc((size_t)(NBKT + 1) * 4);
    int*    bucket_cursor = (int*)alloc((size_t)NBKT * 4);
    int*    csr_tmp       = (int*)alloc((size_t)N_EDGES * 4);
    int*    rowptr        = (int*)alloc(((size_t)N_NODES + 1) * 4);
    int*    csr_src       = (int*)alloc((size_t)N_EDGES * 4);
    float*  p             = (float*)alloc((size_t)N_NODES * 4 * 4);    // [N,4]
    float*  z             = (float*)alloc((size_t)N_NODES * 128 * 4);  // [N,128] max
    float*  h1            = (float*)alloc((size_t)N_NODES * 16 * 4);
    float*  h2            = (float*)alloc((size_t)N_NODES * 32 * 4);
    float*  h3            = (float*)alloc((size_t)N_NODES * 64 * 4);
    (void)ws_size;

    const int B = 256;
    int gN = (N_NODES + B - 1) / B;

    // ---- build dst-CSR via two-level multisplit (no per-edge global atomics) ----
    zero_int_kernel<<<(NBKT + 255) / 256, B, 0, stream>>>(bucket_cnt, NBKT);
    bhist_kernel<<<NCHUNK, B, 0, stream>>>(dst, bucket_cnt);
    bscan_kernel<<<1, 512, 0, stream>>>(bucket_cnt, bucket_base, bucket_cursor);
    partition_kernel<<<NCHUNK, B, 0, stream>>>(src, dst, bucket_cursor, csr_tmp);
    bucket_build_kernel<<<NBKT, B, 0, stream>>>(bucket_base, csr_tmp, rowptr, csr_src);

    // zgather grids: block covers 256/FIN nodes
    const int ZG16 = (N_NODES + (256 / 16) - 1) / (256 / 16);   // 6250
    const int ZG32 = (N_NODES + (256 / 32) - 1) / (256 / 32);   // 12500
    // post grids
    const int NPB1 = 4 * (256 / (16 / 4));   // 256
    const int NPB2 = 4 * (256 / (32 / 4));   // 128
    const int NPB3 = 4 * (256 / (64 / 4));   // 64

    // ---- conv1: 16 -> 16 ----
    p_kernel<16><<<gN, B, 0, stream>>>(x, U1, p);
    zgather_kernel<16><<<ZG16, B, 0, stream>>>(rowptr, csr_src, p, c1, x, z);
    post_kernel<16, 16><<<(N_NODES + NPB1 - 1) / NPB1, B, 0, stream>>>(z, W1, b1, h1);

    // ---- conv2: 16 -> 32 ----
    p_kernel<16><<<gN, B, 0, stream>>>(h1, U2, p);
    zgather_kernel<16><<<ZG16, B, 0, stream>>>(rowptr, csr_src, p, c2, h1, z);
    post_kernel<16, 32><<<(N_NODES + NPB2 - 1) / NPB2, B, 0, stream>>>(z, W2, b2, h2);

    // ---- conv3: 32 -> 64 ----
    p_kernel<32><<<gN, B, 0, stream>>>(h2, U3, p);
    zgather_kernel<32><<<ZG32, B, 0, stream>>>(rowptr, csr_src, p, c3, h2, z);
    post_kernel<32, 64><<<(N_NODES + NPB3 - 1) / NPB3, B, 0, stream>>>(z, W3, b3, h3);

    // ---- tail MLP ----
    tail_kernel<<<gN, B, 0, stream>>>(h3, lw1, lb1, lw2, lb2, lw3, lb3,
                                      lw4, lb4, lw5, lb5, (float*)d_out);
}

// Round 9
// 364.556 us; speedup vs baseline: 3.6151x; 1.1620x over previous
//
#include <hip/hip_runtime.h>
#include <math.h>

#define N_NODES 100000
#define N_EDGES 1600000
#define HEADS 4
#define NBKT ((N_NODES + 255) / 256)        // 391 coarse buckets (256 nodes each)
#define CHUNK_E 4096
#define NCHUNK ((N_EDGES + CHUNK_E - 1) / CHUNK_E)  // 391 edge chunks

// ---------------- CSR build: two-level multisplit ----------------

__global__ void zero_int_kernel(int* __restrict__ ptr, int n) {
    int i = blockIdx.x * blockDim.x + threadIdx.x;
    if (i < n) ptr[i] = 0;
}

// K1: coarse histogram via LDS (one global atomic per (block,bucket))
__global__ __launch_bounds__(256) void bhist_kernel(const int* __restrict__ dst,
                                                    int* __restrict__ bucket_cnt) {
    __shared__ int h[NBKT];
    for (int i = threadIdx.x; i < NBKT; i += 256) h[i] = 0;
    __syncthreads();
    int base = blockIdx.x * CHUNK_E;
    #pragma unroll
    for (int j = 0; j < CHUNK_E / 256; j++) {
        int e = base + j * 256 + threadIdx.x;
        if (e < N_EDGES) atomicAdd(&h[dst[e] >> 8], 1);
    }
    __syncthreads();
    for (int i = threadIdx.x; i < NBKT; i += 256)
        if (h[i]) atomicAdd(&bucket_cnt[i], h[i]);
}

// K2: single-block exclusive scan of bucket counts -> base + cursor
__global__ __launch_bounds__(512) void bscan_kernel(const int* __restrict__ bucket_cnt,
                                                    int* __restrict__ bucket_base,
                                                    int* __restrict__ bucket_cursor) {
    __shared__ int tmp[512];
    int i = threadIdx.x;
    int v = (i < NBKT) ? bucket_cnt[i] : 0;
    tmp[i] = v;
    __syncthreads();
    for (int off = 1; off < 512; off <<= 1) {
        int t = (i >= off) ? tmp[i - off] : 0;
        __syncthreads();
        tmp[i] += t;
        __syncthreads();
    }
    int excl = tmp[i] - v;
    if (i < NBKT) { bucket_base[i] = excl; bucket_cursor[i] = excl; }
    if (i == NBKT) bucket_base[NBKT] = N_EDGES;
}

// K3: partition edges into coarse-bucket regions; packed = (dst&255)<<20 | src.
__global__ __launch_bounds__(256) void partition_kernel(const int* __restrict__ src,
                                                        const int* __restrict__ dst,
                                                        int* __restrict__ bucket_cursor,
                                                        int* __restrict__ csr_tmp) {
    constexpr int EPT = CHUNK_E / 256;   // 16 edges per thread
    __shared__ int h[NBKT];
    __shared__ int gbase[NBKT];
    __shared__ int rcnt[NBKT];
    for (int i = threadIdx.x; i < NBKT; i += 256) { h[i] = 0; rcnt[i] = 0; }
    __syncthreads();
    int base = blockIdx.x * CHUNK_E;
    int d[EPT], s[EPT];
    #pragma unroll
    for (int j = 0; j < EPT; j++) {
        int e = base + j * 256 + threadIdx.x;
        d[j] = (e < N_EDGES) ? dst[e] : -1;
        s[j] = (e < N_EDGES) ? src[e] : 0;
        if (d[j] >= 0) atomicAdd(&h[d[j] >> 8], 1);
    }
    __syncthreads();
    for (int i = threadIdx.x; i < NBKT; i += 256)
        if (h[i]) gbase[i] = atomicAdd(&bucket_cursor[i], h[i]);
    __syncthreads();
    #pragma unroll
    for (int j = 0; j < EPT; j++) {
        if (d[j] >= 0) {
            int b = d[j] >> 8;
            int r = atomicAdd(&rcnt[b], 1);
            csr_tmp[gbase[b] + r] = ((d[j] & 255) << 20) | s[j];
        }
    }
}

// K4: per-bucket (256 nodes): per-node count+scan in LDS -> rowptr;
// sort bucket edges into LDS stage; coalesced copy-out to csr_src.
__global__ __launch_bounds__(256) void bucket_build_kernel(const int* __restrict__ bucket_base,
                                                           const int* __restrict__ csr_tmp,
                                                           int* __restrict__ rowptr,
                                                           int* __restrict__ csr_src) {
    __shared__ int cnt[256];
    __shared__ int tscan[256];
    __shared__ int exc[256];
    __shared__ int stage[8192];
    int b = blockIdx.x;
    int rbeg = bucket_base[b], rend = bucket_base[b + 1];
    int sz = rend - rbeg;
    int tid = threadIdx.x;

    cnt[tid] = 0;
    __syncthreads();
    for (int k = rbeg + tid; k < rend; k += 256) atomicAdd(&cnt[csr_tmp[k] >> 20], 1);
    __syncthreads();
    int v = cnt[tid];
    tscan[tid] = v;
    __syncthreads();
    for (int off = 1; off < 256; off <<= 1) {
        int t = (tid >= off) ? tscan[tid - off] : 0;
        __syncthreads();
        tscan[tid] += t;
        __syncthreads();
    }
    int ex = tscan[tid] - v;
    int node = b * 256 + tid;
    if (node < N_NODES) rowptr[node] = rbeg + ex;
    if (b == 0 && tid == 0) rowptr[N_NODES] = N_EDGES;
    exc[tid] = ex;
    cnt[tid] = 0;
    __syncthreads();

    if (sz <= 8192) {
        for (int k = rbeg + tid; k < rend; k += 256) {
            int pk = csr_tmp[k];
            int dl = pk >> 20;
            int r  = atomicAdd(&cnt[dl], 1);
            stage[exc[dl] + r] = pk & ((1 << 20) - 1);
        }
        __syncthreads();
        for (int i = tid; i < sz; i += 256) csr_src[rbeg + i] = stage[i];
    } else {
        for (int k = rbeg + tid; k < rend; k += 256) {
            int pk = csr_tmp[k];
            int dl = pk >> 20;
            int r  = atomicAdd(&cnt[dl], 1);
            csr_src[rbeg + exc[dl] + r] = pk & ((1 << 20) - 1);
        }
    }
}

// ---------------- p = h @ U  [N,4] ----------------

template<int FIN>
__global__ __launch_bounds__(256) void p_kernel(
        const float* __restrict__ h, const float* __restrict__ U,  // [FIN,4]
        float* __restrict__ p)                                     // [N,4]
{
    int n = blockIdx.x * blockDim.x + threadIdx.x;
    if (n >= N_NODES) return;
    float a0 = 0, a1 = 0, a2 = 0, a3 = 0;
    const float* hr = h + (size_t)n * FIN;
    #pragma unroll
    for (int f = 0; f < FIN; f++) {
        float xv = hr[f];
        a0 += xv * U[f * 4 + 0];
        a1 += xv * U[f * 4 + 1];
        a2 += xv * U[f * 4 + 2];
        a3 += xv * U[f * 4 + 3];
    }
    *(float4*)(p + (size_t)n * 4) = make_float4(a0, a1, a2, a3);
}

// ---------------- fused zgather: per block = NPB nodes' contiguous CSR range.
// Phase 1: q (softmax/deg) for the block's edges into LDS.
// Phase 2: per-(node,f) gather, unrolled x4 (4 outstanding VMEM loads/thread).

template<int FIN>
__global__ __launch_bounds__(256) void zgather_kernel(
        const int* __restrict__ rowptr, const int* __restrict__ csr_src,
        const float* __restrict__ p,     // [N,4]
        const float* __restrict__ cvec,  // [4]
        const float* __restrict__ hprev, // [N, FIN]
        float* __restrict__ z)           // [N, 4*FIN]
{
    constexpr int NPB   = 256 / FIN;    // nodes per block
    constexpr int CHUNK = 512;          // edges per LDS pass (avg block range: NPB*16)
    __shared__ int    sbeg[NPB + 1];
    __shared__ float4 qs[CHUNK];
    __shared__ int    ssrc[CHUNK];

    int tid  = threadIdx.x;
    int nloc = tid / FIN;
    int f    = tid - nloc * FIN;
    int n0   = blockIdx.x * NPB;
    int n    = n0 + nloc;

    if (tid <= NPB) {
        int idx = n0 + tid;
        sbeg[tid] = rowptr[idx > N_NODES ? N_NODES : idx];
    }
    float c0 = cvec[0], c1 = cvec[1], c2 = cvec[2], c3 = cvec[3];
    __syncthreads();

    int BB = sbeg[0], BE = sbeg[NPB];
    int beg = sbeg[nloc], end = sbeg[nloc + 1];

    float a0 = 0, a1 = 0, a2 = 0, a3 = 0;

    for (int cbase = BB; cbase < BE; cbase += CHUNK) {
        int cend = min(cbase + CHUNK, BE);
        __syncthreads();
        // phase 1
        for (int k = cbase + tid; k < cend; k += 256) {
            int s = csr_src[k];
            int lo = 0, hi = NPB;
            while (hi - lo > 1) { int mid = (lo + hi) >> 1; if (k < sbeg[mid]) hi = mid; else lo = mid; }
            float4 ps = *(const float4*)(p + (size_t)s * 4);
            float4 pd = *(const float4*)(p + (size_t)(n0 + lo) * 4);
            float l0 = ps.x - pd.x + c0;
            float l1 = ps.y - pd.y + c1;
            float l2 = ps.z - pd.z + c2;
            float l3 = ps.w - pd.w + c3;
            float m  = fmaxf(fmaxf(l0, l1), fmaxf(l2, l3));
            float e0 = __expf(l0 - m), e1 = __expf(l1 - m);
            float e2 = __expf(l2 - m), e3 = __expf(l3 - m);
            float deg = (float)(sbeg[lo + 1] - sbeg[lo]);
            float inv = 1.0f / (fmaxf(deg, 1.0f) * (e0 + e1 + e2 + e3));
            qs[k - cbase]   = make_float4(e0 * inv, e1 * inv, e2 * inv, e3 * inv);
            ssrc[k - cbase] = s;
        }
        __syncthreads();
        // phase 2, unrolled x4: batch the loads for memory-level parallelism
        int kb = (beg > cbase ? beg : cbase) - cbase;
        int ke = (end < cend ? end : cend) - cbase;
        int k = kb;
        for (; k + 4 <= ke; k += 4) {
            int s0 = ssrc[k], s1 = ssrc[k + 1], s2 = ssrc[k + 2], s3 = ssrc[k + 3];
            float x0 = hprev[(size_t)s0 * FIN + f];
            float x1 = hprev[(size_t)s1 * FIN + f];
            float x2 = hprev[(size_t)s2 * FIN + f];
            float x3 = hprev[(size_t)s3 * FIN + f];
            float4 q0 = qs[k], q1 = qs[k + 1], q2 = qs[k + 2], q3 = qs[k + 3];
            a0 += q0.x * x0; a1 += q0.y * x0; a2 += q0.z * x0; a3 += q0.w * x0;
            a0 += q1.x * x1; a1 += q1.y * x1; a2 += q1.z * x1; a3 += q1.w * x1;
            a0 += q2.x * x2; a1 += q2.y * x2; a2 += q2.z * x2; a3 += q2.w * x2;
            a0 += q3.x * x3; a1 += q3.y * x3; a2 += q3.z * x3; a3 += q3.w * x3;
        }
        for (; k < ke; k++) {
            int s    = ssrc[k];
            float4 q = qs[k];
            float xv = hprev[(size_t)s * FIN + f];
            a0 += q.x * xv; a1 += q.y * xv; a2 += q.z * xv; a3 += q.w * xv;
        }
    }

    if (n < N_NODES) {
        size_t base = (size_t)n * (4 * FIN) + f;
        z[base]           = a0;
        z[base + FIN]     = a1;
        z[base + 2 * FIN] = a2;
        z[base + 3 * FIN] = a3;
    }
}

// ---------------- post: out[n,o] = relu( sum_k z[n,k]*Wp[k,o] + b[o] ),  k = h*FIN+f

template<int FIN, int FOUT>
__global__ __launch_bounds__(256, 4) void post_kernel(
        const float* __restrict__ z,    // [N, 4*FIN]
        const float* __restrict__ W,    // [FIN, 4*FOUT]
        const float* __restrict__ b,    // [FOUT]
        float* __restrict__ out)        // [N, FOUT]
{
    constexpr int K   = 4 * FIN;
    constexpr int OL  = FOUT / 4;
    constexpr int NPB = 4 * (256 / OL);
    constexpr int WSZ = FIN * 4 * FOUT;
    __shared__ float Wp[WSZ];           // [K][FOUT], k = h*FIN+f
    for (int i = threadIdx.x; i < WSZ; i += 256) {
        int f = i / (4 * FOUT);
        int r = i - f * (4 * FOUT);
        int h = r / FOUT;
        int o = r - h * FOUT;
        Wp[(h * FIN + f) * FOUT + o] = W[i];
    }
    __syncthreads();

    int ol = threadIdx.x % OL;
    int g  = threadIdx.x / OL;
    int n0 = blockIdx.x * NPB + g * 4;

    float4 bv = *(const float4*)(b + 4 * ol);
    float4 acc[4];
    const float* zr[4];
    #pragma unroll
    for (int j = 0; j < 4; j++) {
        acc[j] = make_float4(0.f, 0.f, 0.f, 0.f);
        int nn = n0 + j; if (nn > N_NODES - 1) nn = N_NODES - 1;
        zr[j] = z + (size_t)nn * K;
    }

    #pragma unroll 2
    for (int kq = 0; kq < K / 4; kq++) {
        float4 zv[4];
        #pragma unroll
        for (int j = 0; j < 4; j++)
            zv[j] = *(const float4*)(zr[j] + 4 * kq);
        #pragma unroll
        for (int jj = 0; jj < 4; jj++) {
            float4 wv = *(const float4*)(Wp + (4 * kq + jj) * FOUT + 4 * ol);
            #pragma unroll
            for (int j = 0; j < 4; j++) {
                float s = (&zv[j].x)[jj];
                acc[j].x += s * wv.x;
                acc[j].y += s * wv.y;
                acc[j].z += s * wv.z;
                acc[j].w += s * wv.w;
            }
        }
    }

    #pragma unroll
    for (int j = 0; j < 4; j++) {
        int nn = n0 + j;
        if (nn < N_NODES) {
            float4 r;
            r.x = fmaxf(acc[j].x + bv.x, 0.0f);
            r.y = fmaxf(acc[j].y + bv.y, 0.0f);
            r.z = fmaxf(acc[j].z + bv.z, 0.0f);
            r.w = fmaxf(acc[j].w + bv.w, 0.0f);
            *(float4*)(out + (size_t)nn * FOUT + 4 * ol) = r;
        }
    }
}

// ---------------- fused linear tail: 64->32->16->8->4->1, relu..., sigmoid ----------------

__global__ __launch_bounds__(256) void tail_kernel(
        const float* __restrict__ h,   // [N, 64]
        const float* __restrict__ lw1, const float* __restrict__ lb1,
        const float* __restrict__ lw2, const float* __restrict__ lb2,
        const float* __restrict__ lw3, const float* __restrict__ lb3,
        const float* __restrict__ lw4, const float* __restrict__ lb4,
        const float* __restrict__ lw5, const float* __restrict__ lb5,
        float* __restrict__ out)
{
    __shared__ float w1[64 * 32], w2[32 * 16], w3[16 * 8], w4[8 * 4], w5[4];
    __shared__ float B1[32], B2[16], B3[8], B4[4], B5[1];
    for (int i = threadIdx.x; i < 64 * 32; i += blockDim.x) w1[i] = lw1[i];
    for (int i = threadIdx.x; i < 32 * 16; i += blockDim.x) w2[i] = lw2[i];
    for (int i = threadIdx.x; i < 16 * 8;  i += blockDim.x) w3[i] = lw3[i];
    for (int i = threadIdx.x; i < 8 * 4;   i += blockDim.x) w4[i] = lw4[i];
    for (int i = threadIdx.x; i < 4;       i += blockDim.x) w5[i] = lw5[i];
    for (int i = threadIdx.x; i < 32; i += blockDim.x) B1[i] = lb1[i];
    for (int i = threadIdx.x; i < 16; i += blockDim.x) B2[i] = lb2[i];
    for (int i = threadIdx.x; i < 8;  i += blockDim.x) B3[i] = lb3[i];
    for (int i = threadIdx.x; i < 4;  i += blockDim.x) B4[i] = lb4[i];
    if (threadIdx.x == 0) B5[0] = lb5[0];
    __syncthreads();

    int n = blockIdx.x * blockDim.x + threadIdx.x;
    if (n >= N_NODES) return;

    float a[64];
    #pragma unroll
    for (int i = 0; i < 64; i++) a[i] = h[(size_t)n * 64 + i];

    float t1[32];
    for (int o = 0; o < 32; o++) {
        float acc = B1[o];
        #pragma unroll
        for (int i = 0; i < 64; i++) acc += a[i] * w1[i * 32 + o];
        t1[o] = fmaxf(acc, 0.0f);
    }
    float t2[16];
    for (int o = 0; o < 16; o++) {
        float acc = B2[o];
        #pragma unroll
        for (int i = 0; i < 32; i++) acc += t1[i] * w2[i * 16 + o];
        t2[o] = fmaxf(acc, 0.0f);
    }
    float t3[8];
    for (int o = 0; o < 8; o++) {
        float acc = B3[o];
        #pragma unroll
        for (int i = 0; i < 16; i++) acc += t2[i] * w3[i * 8 + o];
        t3[o] = fmaxf(acc, 0.0f);
    }
    float t4[4];
    for (int o = 0; o < 4; o++) {
        float acc = B4[o];
        #pragma unroll
        for (int i = 0; i < 8; i++) acc += t3[i] * w4[i * 4 + o];
        t4[o] = fmaxf(acc, 0.0f);
    }
    float zf = B5[0];
    #pragma unroll
    for (int i = 0; i < 4; i++) zf += t4[i] * w5[i];
    out[n] = 1.0f / (1.0f + expf(-zf));
}

// ---------------- host launch ----------------

extern "C" void kernel_launch(void* const* d_in, const int* in_sizes, int n_in,
                              void* d_out, int out_size, void* d_ws, size_t ws_size,
                              hipStream_t stream) {
    const float* x   = (const float*)d_in[0];
    const int*   ei  = (const int*)d_in[1];
    const int*   src = ei;
    const int*   dst = ei + N_EDGES;
    const float* U1 = (const float*)d_in[2];  const float* c1 = (const float*)d_in[3];
    const float* W1 = (const float*)d_in[4];  const float* b1 = (const float*)d_in[5];
    const float* U2 = (const float*)d_in[6];  const float* c2 = (const float*)d_in[7];
    const float* W2 = (const float*)d_in[8];  const float* b2 = (const float*)d_in[9];
    const float* U3 = (const float*)d_in[10]; const float* c3 = (const float*)d_in[11];
    const float* W3 = (const float*)d_in[12]; const float* b3 = (const float*)d_in[13];
    const float* lw1 = (const float*)d_in[14]; const float* lb1 = (const float*)d_in[15];
    const float* lw2 = (const float*)d_in[16]; const float* lb2 = (const float*)d_in[17];
    const float* lw3 = (const float*)d_in[18]; const float* lb3 = (const float*)d_in[19];
    const float* lw4 = (const float*)d_in[20]; const float* lb4 = (const float*)d_in[21];
    const float* lw5 = (const float*)d_in[22]; const float* lb5 = (const float*)d_in[23];

    char* ws = (char*)d_ws;
    size_t off = 0;
    auto alloc = [&](size_t bytes) -> void* {
        void* ptr = (void*)(ws + off);
        off += (bytes + 255) & ~(size_t)255;
        return ptr;
    };
    int*    bucket_cnt    = (int*)alloc((size_t)(NBKT + 1) * 4);
    int*    bucket_base   = (int*)alloc((size_t)(NBKT + 1) * 4);
    int*    bucket_cursor = (int*)alloc((size_t)NBKT * 4);
    int*    csr_tmp       = (int*)alloc((size_t)N_EDGES * 4);
    int*    rowptr        = (int*)alloc(((size_t)N_NODES + 1) * 4);
    int*    csr_src       = (int*)alloc((size_t)N_EDGES * 4);
    float*  p             = (float*)alloc((size_t)N_NODES * 4 * 4);    // [N,4]
    float*  z             = (float*)alloc((size_t)N_NODES * 128 * 4);  // [N,128] max
    float*  h1            = (float*)alloc((size_t)N_NODES * 16 * 4);
    float*  h2            = (float*)alloc((size_t)N_NODES * 32 * 4);
    float*  h3            = (float*)alloc((size_t)N_NODES * 64 * 4);
    (void)ws_size;

    const int B = 256;
    int gN = (N_NODES + B - 1) / B;

    // ---- build dst-CSR via two-level multisplit (no per-edge global atomics) ----
    zero_int_kernel<<<(NBKT + 255) / 256, B, 0, stream>>>(bucket_cnt, NBKT);
    bhist_kernel<<<NCHUNK, B, 0, stream>>>(dst, bucket_cnt);
    bscan_kernel<<<1, 512, 0, stream>>>(bucket_cnt, bucket_base, bucket_cursor);
    partition_kernel<<<NCHUNK, B, 0, stream>>>(src, dst, bucket_cursor, csr_tmp);
    bucket_build_kernel<<<NBKT, B, 0, stream>>>(bucket_base, csr_tmp, rowptr, csr_src);

    // zgather grids: block covers 256/FIN nodes
    const int ZG16 = (N_NODES + (256 / 16) - 1) / (256 / 16);   // 6250
    const int ZG32 = (N_NODES + (256 / 32) - 1) / (256 / 32);   // 12500
    // post grids
    const int NPB1 = 4 * (256 / (16 / 4));   // 256
    const int NPB2 = 4 * (256 / (32 / 4));   // 128
    const int NPB3 = 4 * (256 / (64 / 4));   // 64

    // ---- conv1: 16 -> 16 ----
    p_kernel<16><<<gN, B, 0, stream>>>(x, U1, p);
    zgather_kernel<16><<<ZG16, B, 0, stream>>>(rowptr, csr_src, p, c1, x, z);
    post_kernel<16, 16><<<(N_NODES + NPB1 - 1) / NPB1, B, 0, stream>>>(z, W1, b1, h1);

    // ---- conv2: 16 -> 32 ----
    p_kernel<16><<<gN, B, 0, stream>>>(h1, U2, p);
    zgather_kernel<16><<<ZG16, B, 0, stream>>>(rowptr, csr_src, p, c2, h1, z);
    post_kernel<16, 32><<<(N_NODES + NPB2 - 1) / NPB2, B, 0, stream>>>(z, W2, b2, h2);

    // ---- conv3: 32 -> 64 ----
    p_kernel<32><<<gN, B, 0, stream>>>(h2, U3, p);
    zgather_kernel<32><<<ZG32, B, 0, stream>>>(rowptr, csr_src, p, c3, h2, z);
    post_kernel<32, 64><<<(N_NODES + NPB3 - 1) / NPB3, B, 0, stream>>>(z, W3, b3, h3);

    // ---- tail MLP ----
    tail_kernel<<<gN, B, 0, stream>>>(h3, lw1, lb1, lw2, lb2, lw3, lb3,
                                      lw4, lb4, lw5, lb5, (float*)d_out);
}

// Round 10
// 355.211 us; speedup vs baseline: 3.7102x; 1.0263x over previous
//
#include <hip/hip_runtime.h>
#include <math.h>

#define N_NODES 100000
#define N_EDGES 1600000
#define HEADS 4
#define NBKT ((N_NODES + 255) / 256)        // 391 coarse buckets (256 nodes each)
#define CHUNK_E 4096
#define NCHUNK ((N_EDGES + CHUNK_E - 1) / CHUNK_E)  // 391 edge chunks

typedef unsigned short ushort_t;

__device__ __forceinline__ ushort_t f2bf(float x) {       // RNE fp32 -> bf16 bits
    unsigned u = __float_as_uint(x);
    u += 0x7FFF + ((u >> 16) & 1);
    return (ushort_t)(u >> 16);
}
__device__ __forceinline__ float bf2f(ushort_t v) {
    return __uint_as_float(((unsigned)v) << 16);
}

// ---------------- CSR build: two-level multisplit ----------------

__global__ void zero_int_kernel(int* __restrict__ ptr, int n) {
    int i = blockIdx.x * blockDim.x + threadIdx.x;
    if (i < n) ptr[i] = 0;
}

__global__ __launch_bounds__(256) void bhist_kernel(const int* __restrict__ dst,
                                                    int* __restrict__ bucket_cnt) {
    __shared__ int h[NBKT];
    for (int i = threadIdx.x; i < NBKT; i += 256) h[i] = 0;
    __syncthreads();
    int base = blockIdx.x * CHUNK_E;
    #pragma unroll
    for (int j = 0; j < CHUNK_E / 256; j++) {
        int e = base + j * 256 + threadIdx.x;
        if (e < N_EDGES) atomicAdd(&h[dst[e] >> 8], 1);
    }
    __syncthreads();
    for (int i = threadIdx.x; i < NBKT; i += 256)
        if (h[i]) atomicAdd(&bucket_cnt[i], h[i]);
}

__global__ __launch_bounds__(512) void bscan_kernel(const int* __restrict__ bucket_cnt,
                                                    int* __restrict__ bucket_base,
                                                    int* __restrict__ bucket_cursor) {
    __shared__ int tmp[512];
    int i = threadIdx.x;
    int v = (i < NBKT) ? bucket_cnt[i] : 0;
    tmp[i] = v;
    __syncthreads();
    for (int off = 1; off < 512; off <<= 1) {
        int t = (i >= off) ? tmp[i - off] : 0;
        __syncthreads();
        tmp[i] += t;
        __syncthreads();
    }
    int excl = tmp[i] - v;
    if (i < NBKT) { bucket_base[i] = excl; bucket_cursor[i] = excl; }
    if (i == NBKT) bucket_base[NBKT] = N_EDGES;
}

__global__ __launch_bounds__(256) void partition_kernel(const int* __restrict__ src,
                                                        const int* __restrict__ dst,
                                                        int* __restrict__ bucket_cursor,
                                                        int* __restrict__ csr_tmp) {
    constexpr int EPT = CHUNK_E / 256;   // 16 edges per thread
    __shared__ int h[NBKT];
    __shared__ int gbase[NBKT];
    __shared__ int rcnt[NBKT];
    for (int i = threadIdx.x; i < NBKT; i += 256) { h[i] = 0; rcnt[i] = 0; }
    __syncthreads();
    int base = blockIdx.x * CHUNK_E;
    int d[EPT], s[EPT];
    #pragma unroll
    for (int j = 0; j < EPT; j++) {
        int e = base + j * 256 + threadIdx.x;
        d[j] = (e < N_EDGES) ? dst[e] : -1;
        s[j] = (e < N_EDGES) ? src[e] : 0;
        if (d[j] >= 0) atomicAdd(&h[d[j] >> 8], 1);
    }
    __syncthreads();
    for (int i = threadIdx.x; i < NBKT; i += 256)
        if (h[i]) gbase[i] = atomicAdd(&bucket_cursor[i], h[i]);
    __syncthreads();
    #pragma unroll
    for (int j = 0; j < EPT; j++) {
        if (d[j] >= 0) {
            int b = d[j] >> 8;
            int r = atomicAdd(&rcnt[b], 1);
            csr_tmp[gbase[b] + r] = ((d[j] & 255) << 20) | s[j];
        }
    }
}

__global__ __launch_bounds__(256) void bucket_build_kernel(const int* __restrict__ bucket_base,
                                                           const int* __restrict__ csr_tmp,
                                                           int* __restrict__ rowptr,
                                                           int* __restrict__ csr_src) {
    __shared__ int cnt[256];
    __shared__ int tscan[256];
    __shared__ int exc[256];
    __shared__ int stage[8192];
    int b = blockIdx.x;
    int rbeg = bucket_base[b], rend = bucket_base[b + 1];
    int sz = rend - rbeg;
    int tid = threadIdx.x;

    cnt[tid] = 0;
    __syncthreads();
    for (int k = rbeg + tid; k < rend; k += 256) atomicAdd(&cnt[csr_tmp[k] >> 20], 1);
    __syncthreads();
    int v = cnt[tid];
    tscan[tid] = v;
    __syncthreads();
    for (int off = 1; off < 256; off <<= 1) {
        int t = (tid >= off) ? tscan[tid - off] : 0;
        __syncthreads();
        tscan[tid] += t;
        __syncthreads();
    }
    int ex = tscan[tid] - v;
    int node = b * 256 + tid;
    if (node < N_NODES) rowptr[node] = rbeg + ex;
    if (b == 0 && tid == 0) rowptr[N_NODES] = N_EDGES;
    exc[tid] = ex;
    cnt[tid] = 0;
    __syncthreads();

    if (sz <= 8192) {
        for (int k = rbeg + tid; k < rend; k += 256) {
            int pk = csr_tmp[k];
            int dl = pk >> 20;
            int r  = atomicAdd(&cnt[dl], 1);
            stage[exc[dl] + r] = pk & ((1 << 20) - 1);
        }
        __syncthreads();
        for (int i = tid; i < sz; i += 256) csr_src[rbeg + i] = stage[i];
    } else {
        for (int k = rbeg + tid; k < rend; k += 256) {
            int pk = csr_tmp[k];
            int dl = pk >> 20;
            int r  = atomicAdd(&cnt[dl], 1);
            csr_src[rbeg + exc[dl] + r] = pk & ((1 << 20) - 1);
        }
    }
}

// ---------------- p = h @ U  [N,4]  (only needed standalone for conv1) ----------------

template<int FIN>
__global__ __launch_bounds__(256) void p_kernel(
        const float* __restrict__ h, const float* __restrict__ U,  // [FIN,4]
        float* __restrict__ p)                                     // [N,4]
{
    int n = blockIdx.x * blockDim.x + threadIdx.x;
    if (n >= N_NODES) return;
    float a0 = 0, a1 = 0, a2 = 0, a3 = 0;
    const float* hr = h + (size_t)n * FIN;
    #pragma unroll
    for (int f = 0; f < FIN; f++) {
        float xv = hr[f];
        a0 += xv * U[f * 4 + 0];
        a1 += xv * U[f * 4 + 1];
        a2 += xv * U[f * 4 + 2];
        a3 += xv * U[f * 4 + 3];
    }
    *(float4*)(p + (size_t)n * 4) = make_float4(a0, a1, a2, a3);
}

// ---------------- fused zgather (fp32 hprev) ----------------

template<int FIN>
__global__ __launch_bounds__(256) void zgather_kernel(
        const int* __restrict__ rowptr, const int* __restrict__ csr_src,
        const float* __restrict__ p, const float* __restrict__ cvec,
        const float* __restrict__ hprev,  // [N, FIN] fp32
        float* __restrict__ z)            // [N, 4*FIN]
{
    constexpr int NPB   = 256 / FIN;
    constexpr int CHUNK = 512;
    __shared__ int    sbeg[NPB + 1];
    __shared__ float4 qs[CHUNK];
    __shared__ int    ssrc[CHUNK];

    int tid  = threadIdx.x;
    int nloc = tid / FIN;
    int f    = tid - nloc * FIN;
    int n0   = blockIdx.x * NPB;
    int n    = n0 + nloc;

    if (tid <= NPB) {
        int idx = n0 + tid;
        sbeg[tid] = rowptr[idx > N_NODES ? N_NODES : idx];
    }
    float c0 = cvec[0], c1 = cvec[1], c2 = cvec[2], c3 = cvec[3];
    __syncthreads();

    int BB = sbeg[0], BE = sbeg[NPB];
    int beg = sbeg[nloc], end = sbeg[nloc + 1];
    float a0 = 0, a1 = 0, a2 = 0, a3 = 0;

    for (int cbase = BB; cbase < BE; cbase += CHUNK) {
        int cend = min(cbase + CHUNK, BE);
        __syncthreads();
        for (int k = cbase + tid; k < cend; k += 256) {
            int s = csr_src[k];
            int lo = 0, hi = NPB;
            while (hi - lo > 1) { int mid = (lo + hi) >> 1; if (k < sbeg[mid]) hi = mid; else lo = mid; }
            float4 ps = *(const float4*)(p + (size_t)s * 4);
            float4 pd = *(const float4*)(p + (size_t)(n0 + lo) * 4);
            float l0 = ps.x - pd.x + c0;
            float l1 = ps.y - pd.y + c1;
            float l2 = ps.z - pd.z + c2;
            float l3 = ps.w - pd.w + c3;
            float m  = fmaxf(fmaxf(l0, l1), fmaxf(l2, l3));
            float e0 = __expf(l0 - m), e1 = __expf(l1 - m);
            float e2 = __expf(l2 - m), e3 = __expf(l3 - m);
            float deg = (float)(sbeg[lo + 1] - sbeg[lo]);
            float inv = 1.0f / (fmaxf(deg, 1.0f) * (e0 + e1 + e2 + e3));
            qs[k - cbase]   = make_float4(e0 * inv, e1 * inv, e2 * inv, e3 * inv);
            ssrc[k - cbase] = s;
        }
        __syncthreads();
        int kb = (beg > cbase ? beg : cbase) - cbase;
        int ke = (end < cend ? end : cend) - cbase;
        int k = kb;
        for (; k + 4 <= ke; k += 4) {
            int s0 = ssrc[k], s1 = ssrc[k + 1], s2 = ssrc[k + 2], s3 = ssrc[k + 3];
            float x0 = hprev[(size_t)s0 * FIN + f];
            float x1 = hprev[(size_t)s1 * FIN + f];
            float x2 = hprev[(size_t)s2 * FIN + f];
            float x3 = hprev[(size_t)s3 * FIN + f];
            float4 q0 = qs[k], q1 = qs[k + 1], q2 = qs[k + 2], q3 = qs[k + 3];
            a0 += q0.x * x0; a1 += q0.y * x0; a2 += q0.z * x0; a3 += q0.w * x0;
            a0 += q1.x * x1; a1 += q1.y * x1; a2 += q1.z * x1; a3 += q1.w * x1;
            a0 += q2.x * x2; a1 += q2.y * x2; a2 += q2.z * x2; a3 += q2.w * x2;
            a0 += q3.x * x3; a1 += q3.y * x3; a2 += q3.z * x3; a3 += q3.w * x3;
        }
        for (; k < ke; k++) {
            int s    = ssrc[k];
            float4 q = qs[k];
            float xv = hprev[(size_t)s * FIN + f];
            a0 += q.x * xv; a1 += q.y * xv; a2 += q.z * xv; a3 += q.w * xv;
        }
    }

    if (n < N_NODES) {
        size_t base = (size_t)n * (4 * FIN) + f;
        z[base]           = a0;
        z[base + FIN]     = a1;
        z[base + 2 * FIN] = a2;
        z[base + 3 * FIN] = a3;
    }
}

// ---------------- fused zgather (bf16 hprev) — conv3: 1 cache line per edge ----------------

template<int FIN>
__global__ __launch_bounds__(256) void zgather_bf16_kernel(
        const int* __restrict__ rowptr, const int* __restrict__ csr_src,
        const float* __restrict__ p, const float* __restrict__ cvec,
        const ushort_t* __restrict__ hprev,  // [N, FIN] bf16
        float* __restrict__ z)               // [N, 4*FIN]
{
    constexpr int NPB   = 256 / FIN;
    constexpr int CHUNK = 512;
    __shared__ int    sbeg[NPB + 1];
    __shared__ float4 qs[CHUNK];
    __shared__ int    ssrc[CHUNK];

    int tid  = threadIdx.x;
    int nloc = tid / FIN;
    int f    = tid - nloc * FIN;
    int n0   = blockIdx.x * NPB;
    int n    = n0 + nloc;

    if (tid <= NPB) {
        int idx = n0 + tid;
        sbeg[tid] = rowptr[idx > N_NODES ? N_NODES : idx];
    }
    float c0 = cvec[0], c1 = cvec[1], c2 = cvec[2], c3 = cvec[3];
    __syncthreads();

    int BB = sbeg[0], BE = sbeg[NPB];
    int beg = sbeg[nloc], end = sbeg[nloc + 1];
    float a0 = 0, a1 = 0, a2 = 0, a3 = 0;

    for (int cbase = BB; cbase < BE; cbase += CHUNK) {
        int cend = min(cbase + CHUNK, BE);
        __syncthreads();
        for (int k = cbase + tid; k < cend; k += 256) {
            int s = csr_src[k];
            int lo = 0, hi = NPB;
            while (hi - lo > 1) { int mid = (lo + hi) >> 1; if (k < sbeg[mid]) hi = mid; else lo = mid; }
            float4 ps = *(const float4*)(p + (size_t)s * 4);
            float4 pd = *(const float4*)(p + (size_t)(n0 + lo) * 4);
            float l0 = ps.x - pd.x + c0;
            float l1 = ps.y - pd.y + c1;
            float l2 = ps.z - pd.z + c2;
            float l3 = ps.w - pd.w + c3;
            float m  = fmaxf(fmaxf(l0, l1), fmaxf(l2, l3));
            float e0 = __expf(l0 - m), e1 = __expf(l1 - m);
            float e2 = __expf(l2 - m), e3 = __expf(l3 - m);
            float deg = (float)(sbeg[lo + 1] - sbeg[lo]);
            float inv = 1.0f / (fmaxf(deg, 1.0f) * (e0 + e1 + e2 + e3));
            qs[k - cbase]   = make_float4(e0 * inv, e1 * inv, e2 * inv, e3 * inv);
            ssrc[k - cbase] = s;
        }
        __syncthreads();
        int kb = (beg > cbase ? beg : cbase) - cbase;
        int ke = (end < cend ? end : cend) - cbase;
        int k = kb;
        for (; k + 4 <= ke; k += 4) {
            int s0 = ssrc[k], s1 = ssrc[k + 1], s2 = ssrc[k + 2], s3 = ssrc[k + 3];
            ushort_t u0 = hprev[(size_t)s0 * FIN + f];
            ushort_t u1 = hprev[(size_t)s1 * FIN + f];
            ushort_t u2 = hprev[(size_t)s2 * FIN + f];
            ushort_t u3 = hprev[(size_t)s3 * FIN + f];
            float x0 = bf2f(u0), x1 = bf2f(u1), x2 = bf2f(u2), x3 = bf2f(u3);
            float4 q0 = qs[k], q1 = qs[k + 1], q2 = qs[k + 2], q3 = qs[k + 3];
            a0 += q0.x * x0; a1 += q0.y * x0; a2 += q0.z * x0; a3 += q0.w * x0;
            a0 += q1.x * x1; a1 += q1.y * x1; a2 += q1.z * x1; a3 += q1.w * x1;
            a0 += q2.x * x2; a1 += q2.y * x2; a2 += q2.z * x2; a3 += q2.w * x2;
            a0 += q3.x * x3; a1 += q3.y * x3; a2 += q3.z * x3; a3 += q3.w * x3;
        }
        for (; k < ke; k++) {
            int s    = ssrc[k];
            float4 q = qs[k];
            float xv = bf2f(hprev[(size_t)s * FIN + f]);
            a0 += q.x * xv; a1 += q.y * xv; a2 += q.z * xv; a3 += q.w * xv;
        }
    }

    if (n < N_NODES) {
        size_t base = (size_t)n * (4 * FIN) + f;
        z[base]           = a0;
        z[base + FIN]     = a1;
        z[base + 2 * FIN] = a2;
        z[base + 3 * FIN] = a3;
    }
}

// ---------------- post: out[n,o] = relu( sum_k z[n,k]*Wp[k,o] + b[o] )
// MODE 0: write fp32 out only (conv3)
// MODE 1: write fp32 out + compute p_next = out @ Unext (conv1)
// MODE 2: write bf16 out + compute p_next (conv2; fp32 h2 not needed downstream)

template<int FIN, int FOUT, int MODE>
__global__ __launch_bounds__(256, 4) void post_kernel(
        const float* __restrict__ z,      // [N, 4*FIN]
        const float* __restrict__ W,      // [FIN, 4*FOUT]
        const float* __restrict__ b,      // [FOUT]
        float* __restrict__ out,          // [N, FOUT] (MODE 0/1)
        ushort_t* __restrict__ out_bf,    // [N, FOUT] (MODE 2)
        const float* __restrict__ Unext,  // [FOUT, 4] (MODE 1/2)
        float* __restrict__ pnext)        // [N, 4]    (MODE 1/2)
{
    constexpr int K   = 4 * FIN;
    constexpr int OL  = FOUT / 4;
    constexpr int NPB = 4 * (256 / OL);
    constexpr int WSZ = FIN * 4 * FOUT;
    __shared__ float Wp[WSZ];           // [K][FOUT], k = h*FIN+f
    __shared__ float htile[MODE ? NPB * FOUT : 1];
    __shared__ float Uloc[MODE ? FOUT * 4 : 1];
    for (int i = threadIdx.x; i < WSZ; i += 256) {
        int f = i / (4 * FOUT);
        int r = i - f * (4 * FOUT);
        int h = r / FOUT;
        int o = r - h * FOUT;
        Wp[(h * FIN + f) * FOUT + o] = W[i];
    }
    if (MODE) {
        for (int i = threadIdx.x; i < FOUT * 4; i += 256) Uloc[i] = Unext[i];
    }
    __syncthreads();

    int ol = threadIdx.x % OL;
    int g  = threadIdx.x / OL;
    int n0 = blockIdx.x * NPB + g * 4;

    float4 bv = *(const float4*)(b + 4 * ol);
    float4 acc[4];
    const float* zr[4];
    #pragma unroll
    for (int j = 0; j < 4; j++) {
        acc[j] = make_float4(0.f, 0.f, 0.f, 0.f);
        int nn = n0 + j; if (nn > N_NODES - 1) nn = N_NODES - 1;
        zr[j] = z + (size_t)nn * K;
    }

    #pragma unroll 2
    for (int kq = 0; kq < K / 4; kq++) {
        float4 zv[4];
        #pragma unroll
        for (int j = 0; j < 4; j++)
            zv[j] = *(const float4*)(zr[j] + 4 * kq);
        #pragma unroll
        for (int jj = 0; jj < 4; jj++) {
            float4 wv = *(const float4*)(Wp + (4 * kq + jj) * FOUT + 4 * ol);
            #pragma unroll
            for (int j = 0; j < 4; j++) {
                float s = (&zv[j].x)[jj];
                acc[j].x += s * wv.x;
                acc[j].y += s * wv.y;
                acc[j].z += s * wv.z;
                acc[j].w += s * wv.w;
            }
        }
    }

    #pragma unroll
    for (int j = 0; j < 4; j++) {
        int nn = n0 + j;
        float4 r;
        r.x = fmaxf(acc[j].x + bv.x, 0.0f);
        r.y = fmaxf(acc[j].y + bv.y, 0.0f);
        r.z = fmaxf(acc[j].z + bv.z, 0.0f);
        r.w = fmaxf(acc[j].w + bv.w, 0.0f);
        if (MODE)
            *(float4*)(htile + (g * 4 + j) * FOUT + 4 * ol) = r;
        if (nn < N_NODES) {
            if (MODE == 2) {
                ushort4 u;
                u.x = f2bf(r.x); u.y = f2bf(r.y); u.z = f2bf(r.z); u.w = f2bf(r.w);
                *(ushort4*)(out_bf + (size_t)nn * FOUT + 4 * ol) = u;
            } else {
                *(float4*)(out + (size_t)nn * FOUT + 4 * ol) = r;
            }
        }
    }

    if (MODE) {
        __syncthreads();
        int tid = threadIdx.x;
        if (tid < NPB) {
            int nn = blockIdx.x * NPB + tid;
            if (nn < N_NODES) {
                float a0 = 0, a1 = 0, a2 = 0, a3 = 0;
                const float* hr = htile + tid * FOUT;
                #pragma unroll
                for (int f = 0; f < FOUT; f++) {
                    float xv = hr[f];
                    a0 += xv * Uloc[f * 4 + 0];
                    a1 += xv * Uloc[f * 4 + 1];
                    a2 += xv * Uloc[f * 4 + 2];
                    a3 += xv * Uloc[f * 4 + 3];
                }
                *(float4*)(pnext + (size_t)nn * 4) = make_float4(a0, a1, a2, a3);
            }
        }
    }
}

// ---------------- fused linear tail: 64->32->16->8->4->1, relu..., sigmoid ----------------

__global__ __launch_bounds__(256) void tail_kernel(
        const float* __restrict__ h,   // [N, 64]
        const float* __restrict__ lw1, const float* __restrict__ lb1,
        const float* __restrict__ lw2, const float* __restrict__ lb2,
        const float* __restrict__ lw3, const float* __restrict__ lb3,
        const float* __restrict__ lw4, const float* __restrict__ lb4,
        const float* __restrict__ lw5, const float* __restrict__ lb5,
        float* __restrict__ out)
{
    __shared__ float w1[64 * 32], w2[32 * 16], w3[16 * 8], w4[8 * 4], w5[4];
    __shared__ float B1[32], B2[16], B3[8], B4[4], B5[1];
    for (int i = threadIdx.x; i < 64 * 32; i += blockDim.x) w1[i] = lw1[i];
    for (int i = threadIdx.x; i < 32 * 16; i += blockDim.x) w2[i] = lw2[i];
    for (int i = threadIdx.x; i < 16 * 8;  i += blockDim.x) w3[i] = lw3[i];
    for (int i = threadIdx.x; i < 8 * 4;   i += blockDim.x) w4[i] = lw4[i];
    for (int i = threadIdx.x; i < 4;       i += blockDim.x) w5[i] = lw5[i];
    for (int i = threadIdx.x; i < 32; i += blockDim.x) B1[i] = lb1[i];
    for (int i = threadIdx.x; i < 16; i += blockDim.x) B2[i] = lb2[i];
    for (int i = threadIdx.x; i < 8;  i += blockDim.x) B3[i] = lb3[i];
    for (int i = threadIdx.x; i < 4;  i += blockDim.x) B4[i] = lb4[i];
    if (threadIdx.x == 0) B5[0] = lb5[0];
    __syncthreads();

    int n = blockIdx.x * blockDim.x + threadIdx.x;
    if (n >= N_NODES) return;

    float a[64];
    #pragma unroll
    for (int i = 0; i < 64; i++) a[i] = h[(size_t)n * 64 + i];

    float t1[32];
    for (int o = 0; o < 32; o++) {
        float acc = B1[o];
        #pragma unroll
        for (int i = 0; i < 64; i++) acc += a[i] * w1[i * 32 + o];
        t1[o] = fmaxf(acc, 0.0f);
    }
    float t2[16];
    for (int o = 0; o < 16; o++) {
        float acc = B2[o];
        #pragma unroll
        for (int i = 0; i < 32; i++) acc += t1[i] * w2[i * 16 + o];
        t2[o] = fmaxf(acc, 0.0f);
    }
    float t3[8];
    for (int o = 0; o < 8; o++) {
        float acc = B3[o];
        #pragma unroll
        for (int i = 0; i < 16; i++) acc += t2[i] * w3[i * 8 + o];
        t3[o] = fmaxf(acc, 0.0f);
    }
    float t4[4];
    for (int o = 0; o < 4; o++) {
        float acc = B4[o];
        #pragma unroll
        for (int i = 0; i < 8; i++) acc += t3[i] * w4[i * 4 + o];
        t4[o] = fmaxf(acc, 0.0f);
    }
    float zf = B5[0];
    #pragma unroll
    for (int i = 0; i < 4; i++) zf += t4[i] * w5[i];
    out[n] = 1.0f / (1.0f + expf(-zf));
}

// ---------------- host launch ----------------

extern "C" void kernel_launch(void* const* d_in, const int* in_sizes, int n_in,
                              void* d_out, int out_size, void* d_ws, size_t ws_size,
                              hipStream_t stream) {
    const float* x   = (const float*)d_in[0];
    const int*   ei  = (const int*)d_in[1];
    const int*   src = ei;
    const int*   dst = ei + N_EDGES;
    const float* U1 = (const float*)d_in[2];  const float* c1 = (const float*)d_in[3];
    const float* W1 = (const float*)d_in[4];  const float* b1 = (const float*)d_in[5];
    const float* U2 = (const float*)d_in[6];  const float* c2 = (const float*)d_in[7];
    const float* W2 = (const float*)d_in[8];  const float* b2 = (const float*)d_in[9];
    const float* U3 = (const float*)d_in[10]; const float* c3 = (const float*)d_in[11];
    const float* W3 = (const float*)d_in[12]; const float* b3 = (const float*)d_in[13];
    const float* lw1 = (const float*)d_in[14]; const float* lb1 = (const float*)d_in[15];
    const float* lw2 = (const float*)d_in[16]; const float* lb2 = (const float*)d_in[17];
    const float* lw3 = (const float*)d_in[18]; const float* lb3 = (const float*)d_in[19];
    const float* lw4 = (const float*)d_in[20]; const float* lb4 = (const float*)d_in[21];
    const float* lw5 = (const float*)d_in[22]; const float* lb5 = (const float*)d_in[23];

    char* ws = (char*)d_ws;
    size_t off = 0;
    auto alloc = [&](size_t bytes) -> void* {
        void* ptr = (void*)(ws + off);
        off += (bytes + 255) & ~(size_t)255;
        return ptr;
    };
    int*      bucket_cnt    = (int*)alloc((size_t)(NBKT + 1) * 4);
    int*      bucket_base   = (int*)alloc((size_t)(NBKT + 1) * 4);
    int*      bucket_cursor = (int*)alloc((size_t)NBKT * 4);
    int*      csr_tmp       = (int*)alloc((size_t)N_EDGES * 4);
    int*      rowptr        = (int*)alloc(((size_t)N_NODES + 1) * 4);
    int*      csr_src       = (int*)alloc((size_t)N_EDGES * 4);
    float*    p             = (float*)alloc((size_t)N_NODES * 4 * 4);    // [N,4]
    float*    z             = (float*)alloc((size_t)N_NODES * 128 * 4);  // [N,128] max
    float*    h1            = (float*)alloc((size_t)N_NODES * 16 * 4);
    ushort_t* h2bf          = (ushort_t*)alloc((size_t)N_NODES * 32 * 2);
    float*    h3            = (float*)alloc((size_t)N_NODES * 64 * 4);
    (void)ws_size;

    const int B = 256;
    int gN = (N_NODES + B - 1) / B;

    // ---- build dst-CSR via two-level multisplit (no per-edge global atomics) ----
    zero_int_kernel<<<(NBKT + 255) / 256, B, 0, stream>>>(bucket_cnt, NBKT);
    bhist_kernel<<<NCHUNK, B, 0, stream>>>(dst, bucket_cnt);
    bscan_kernel<<<1, 512, 0, stream>>>(bucket_cnt, bucket_base, bucket_cursor);
    partition_kernel<<<NCHUNK, B, 0, stream>>>(src, dst, bucket_cursor, csr_tmp);
    bucket_build_kernel<<<NBKT, B, 0, stream>>>(bucket_base, csr_tmp, rowptr, csr_src);

    const int ZG16 = (N_NODES + (256 / 16) - 1) / (256 / 16);   // 6250
    const int ZG32 = (N_NODES + (256 / 32) - 1) / (256 / 32);   // 12500
    const int NPB1 = 4 * (256 / (16 / 4));   // 256
    const int NPB2 = 4 * (256 / (32 / 4));   // 128
    const int NPB3 = 4 * (256 / (64 / 4));   // 64

    // ---- conv1: 16 -> 16 ----  (post1 also computes p2 = h1@U2)
    p_kernel<16><<<gN, B, 0, stream>>>(x, U1, p);
    zgather_kernel<16><<<ZG16, B, 0, stream>>>(rowptr, csr_src, p, c1, x, z);
    post_kernel<16, 16, 1><<<(N_NODES + NPB1 - 1) / NPB1, B, 0, stream>>>(
        z, W1, b1, h1, nullptr, U2, p);

    // ---- conv2: 16 -> 32 ----  (post2 writes h2 in bf16 + computes p3 = h2@U3)
    zgather_kernel<16><<<ZG16, B, 0, stream>>>(rowptr, csr_src, p, c2, h1, z);
    post_kernel<16, 32, 2><<<(N_NODES + NPB2 - 1) / NPB2, B, 0, stream>>>(
        z, W2, b2, nullptr, h2bf, U3, p);

    // ---- conv3: 32 -> 64 ----  (bf16 gather: 1 line/edge)
    zgather_bf16_kernel<32><<<ZG32, B, 0, stream>>>(rowptr, csr_src, p, c3, h2bf, z);
    post_kernel<32, 64, 0><<<(N_NODES + NPB3 - 1) / NPB3, B, 0, stream>>>(
        z, W3, b3, h3, nullptr, nullptr, nullptr);

    // ---- tail MLP ----
    tail_kernel<<<gN, B, 0, stream>>>(h3, lw1, lb1, lw2, lb2, lw3, lb3,
                                      lw4, lb4, lw5, lb5, (float*)d_out);
}

// Round 11
// 346.299 us; speedup vs baseline: 3.8057x; 1.0257x over previous
//
#include <hip/hip_runtime.h>
#include <math.h>

#define N_NODES 100000
#define N_EDGES 1600000
#define HEADS 4
#define NBKT ((N_NODES + 255) / 256)        // 391 coarse buckets (256 nodes each)
#define CHUNK_E 4096
#define NCHUNK ((N_EDGES + CHUNK_E - 1) / CHUNK_E)  // 391 edge chunks

typedef unsigned short ushort_t;

__device__ __forceinline__ ushort_t f2bf(float x) {       // RNE fp32 -> bf16 bits
    unsigned u = __float_as_uint(x);
    u += 0x7FFF + ((u >> 16) & 1);
    return (ushort_t)(u >> 16);
}
__device__ __forceinline__ float bf2f(ushort_t v) {
    return __uint_as_float(((unsigned)v) << 16);
}
__device__ __forceinline__ void unpack2(unsigned u, float& lo, float& hi) {
    lo = __uint_as_float(u << 16);
    hi = __uint_as_float(u & 0xffff0000u);
}

// ---------------- CSR build: two-level multisplit ----------------

__global__ void zero_int_kernel(int* __restrict__ ptr, int n) {
    int i = blockIdx.x * blockDim.x + threadIdx.x;
    if (i < n) ptr[i] = 0;
}

__global__ __launch_bounds__(256) void bhist_kernel(const int* __restrict__ dst,
                                                    int* __restrict__ bucket_cnt) {
    __shared__ int h[NBKT];
    for (int i = threadIdx.x; i < NBKT; i += 256) h[i] = 0;
    __syncthreads();
    int base = blockIdx.x * CHUNK_E;
    #pragma unroll
    for (int j = 0; j < CHUNK_E / 256; j++) {
        int e = base + j * 256 + threadIdx.x;
        if (e < N_EDGES) atomicAdd(&h[dst[e] >> 8], 1);
    }
    __syncthreads();
    for (int i = threadIdx.x; i < NBKT; i += 256)
        if (h[i]) atomicAdd(&bucket_cnt[i], h[i]);
}

__global__ __launch_bounds__(512) void bscan_kernel(const int* __restrict__ bucket_cnt,
                                                    int* __restrict__ bucket_base,
                                                    int* __restrict__ bucket_cursor) {
    __shared__ int tmp[512];
    int i = threadIdx.x;
    int v = (i < NBKT) ? bucket_cnt[i] : 0;
    tmp[i] = v;
    __syncthreads();
    for (int off = 1; off < 512; off <<= 1) {
        int t = (i >= off) ? tmp[i - off] : 0;
        __syncthreads();
        tmp[i] += t;
        __syncthreads();
    }
    int excl = tmp[i] - v;
    if (i < NBKT) { bucket_base[i] = excl; bucket_cursor[i] = excl; }
    if (i == NBKT) bucket_base[NBKT] = N_EDGES;
}

__global__ __launch_bounds__(256) void partition_kernel(const int* __restrict__ src,
                                                        const int* __restrict__ dst,
                                                        int* __restrict__ bucket_cursor,
                                                        int* __restrict__ csr_tmp) {
    constexpr int EPT = CHUNK_E / 256;   // 16 edges per thread
    __shared__ int h[NBKT];
    __shared__ int gbase[NBKT];
    __shared__ int rcnt[NBKT];
    for (int i = threadIdx.x; i < NBKT; i += 256) { h[i] = 0; rcnt[i] = 0; }
    __syncthreads();
    int base = blockIdx.x * CHUNK_E;
    int d[EPT], s[EPT];
    #pragma unroll
    for (int j = 0; j < EPT; j++) {
        int e = base + j * 256 + threadIdx.x;
        d[j] = (e < N_EDGES) ? dst[e] : -1;
        s[j] = (e < N_EDGES) ? src[e] : 0;
        if (d[j] >= 0) atomicAdd(&h[d[j] >> 8], 1);
    }
    __syncthreads();
    for (int i = threadIdx.x; i < NBKT; i += 256)
        if (h[i]) gbase[i] = atomicAdd(&bucket_cursor[i], h[i]);
    __syncthreads();
    #pragma unroll
    for (int j = 0; j < EPT; j++) {
        if (d[j] >= 0) {
            int b = d[j] >> 8;
            int r = atomicAdd(&rcnt[b], 1);
            csr_tmp[gbase[b] + r] = ((d[j] & 255) << 20) | s[j];
        }
    }
}

__global__ __launch_bounds__(256) void bucket_build_kernel(const int* __restrict__ bucket_base,
                                                           const int* __restrict__ csr_tmp,
                                                           int* __restrict__ rowptr,
                                                           int* __restrict__ csr_src) {
    __shared__ int cnt[256];
    __shared__ int tscan[256];
    __shared__ int exc[256];
    __shared__ int stage[8192];
    int b = blockIdx.x;
    int rbeg = bucket_base[b], rend = bucket_base[b + 1];
    int sz = rend - rbeg;
    int tid = threadIdx.x;

    cnt[tid] = 0;
    __syncthreads();
    for (int k = rbeg + tid; k < rend; k += 256) atomicAdd(&cnt[csr_tmp[k] >> 20], 1);
    __syncthreads();
    int v = cnt[tid];
    tscan[tid] = v;
    __syncthreads();
    for (int off = 1; off < 256; off <<= 1) {
        int t = (tid >= off) ? tscan[tid - off] : 0;
        __syncthreads();
        tscan[tid] += t;
        __syncthreads();
    }
    int ex = tscan[tid] - v;
    int node = b * 256 + tid;
    if (node < N_NODES) rowptr[node] = rbeg + ex;
    if (b == 0 && tid == 0) rowptr[N_NODES] = N_EDGES;
    exc[tid] = ex;
    cnt[tid] = 0;
    __syncthreads();

    if (sz <= 8192) {
        for (int k = rbeg + tid; k < rend; k += 256) {
            int pk = csr_tmp[k];
            int dl = pk >> 20;
            int r  = atomicAdd(&cnt[dl], 1);
            stage[exc[dl] + r] = pk & ((1 << 20) - 1);
        }
        __syncthreads();
        for (int i = tid; i < sz; i += 256) csr_src[rbeg + i] = stage[i];
    } else {
        for (int k = rbeg + tid; k < rend; k += 256) {
            int pk = csr_tmp[k];
            int dl = pk >> 20;
            int r  = atomicAdd(&cnt[dl], 1);
            csr_src[rbeg + exc[dl] + r] = pk & ((1 << 20) - 1);
        }
    }
}

// ---------------- p1 = x @ U1  [N,4], fused cast x -> bf16 ----------------

__global__ __launch_bounds__(256) void p_cast_kernel(
        const float* __restrict__ x, const float* __restrict__ U,  // [16,4]
        float* __restrict__ p,        // [N,4]
        ushort_t* __restrict__ xbf)   // [N,16]
{
    int n = blockIdx.x * blockDim.x + threadIdx.x;
    if (n >= N_NODES) return;
    float a0 = 0, a1 = 0, a2 = 0, a3 = 0;
    const float* hr = x + (size_t)n * 16;
    float xv[16];
    #pragma unroll
    for (int f = 0; f < 16; f++) {
        xv[f] = hr[f];
        a0 += xv[f] * U[f * 4 + 0];
        a1 += xv[f] * U[f * 4 + 1];
        a2 += xv[f] * U[f * 4 + 2];
        a3 += xv[f] * U[f * 4 + 3];
    }
    *(float4*)(p + (size_t)n * 4) = make_float4(a0, a1, a2, a3);
    #pragma unroll
    for (int j = 0; j < 4; j++) {
        ushort4 u;
        u.x = f2bf(xv[4 * j + 0]); u.y = f2bf(xv[4 * j + 1]);
        u.z = f2bf(xv[4 * j + 2]); u.w = f2bf(xv[4 * j + 3]);
        *(ushort4*)(xbf + (size_t)n * 16 + 4 * j) = u;
    }
}

// ---------------- fused zgather (bf16 hprev), unroll x8 ----------------

template<int FIN>
__global__ __launch_bounds__(256) void zgather_bf16_kernel(
        const int* __restrict__ rowptr, const int* __restrict__ csr_src,
        const float* __restrict__ p, const float* __restrict__ cvec,
        const ushort_t* __restrict__ hprev,  // [N, FIN] bf16
        float* __restrict__ z)               // [N, 4*FIN]
{
    constexpr int NPB   = 256 / FIN;
    constexpr int CHUNK = 512;
    __shared__ int    sbeg[NPB + 1];
    __shared__ float4 qs[CHUNK];
    __shared__ int    ssrc[CHUNK];

    int tid  = threadIdx.x;
    int nloc = tid / FIN;
    int f    = tid - nloc * FIN;
    int n0   = blockIdx.x * NPB;
    int n    = n0 + nloc;

    if (tid <= NPB) {
        int idx = n0 + tid;
        sbeg[tid] = rowptr[idx > N_NODES ? N_NODES : idx];
    }
    float c0 = cvec[0], c1 = cvec[1], c2 = cvec[2], c3 = cvec[3];
    __syncthreads();

    int BB = sbeg[0], BE = sbeg[NPB];
    int beg = sbeg[nloc], end = sbeg[nloc + 1];
    float a0 = 0, a1 = 0, a2 = 0, a3 = 0;

    for (int cbase = BB; cbase < BE; cbase += CHUNK) {
        int cend = min(cbase + CHUNK, BE);
        __syncthreads();
        // phase 1: q for this chunk
        for (int k = cbase + tid; k < cend; k += 256) {
            int s = csr_src[k];
            int lo = 0, hi = NPB;
            while (hi - lo > 1) { int mid = (lo + hi) >> 1; if (k < sbeg[mid]) hi = mid; else lo = mid; }
            float4 ps = *(const float4*)(p + (size_t)s * 4);
            float4 pd = *(const float4*)(p + (size_t)(n0 + lo) * 4);
            float l0 = ps.x - pd.x + c0;
            float l1 = ps.y - pd.y + c1;
            float l2 = ps.z - pd.z + c2;
            float l3 = ps.w - pd.w + c3;
            float m  = fmaxf(fmaxf(l0, l1), fmaxf(l2, l3));
            float e0 = __expf(l0 - m), e1 = __expf(l1 - m);
            float e2 = __expf(l2 - m), e3 = __expf(l3 - m);
            float deg = (float)(sbeg[lo + 1] - sbeg[lo]);
            float inv = 1.0f / (fmaxf(deg, 1.0f) * (e0 + e1 + e2 + e3));
            qs[k - cbase]   = make_float4(e0 * inv, e1 * inv, e2 * inv, e3 * inv);
            ssrc[k - cbase] = s;
        }
        __syncthreads();
        // phase 2: unroll x8 (8 outstanding loads / thread)
        int kb = (beg > cbase ? beg : cbase) - cbase;
        int ke = (end < cend ? end : cend) - cbase;
        int k = kb;
        for (; k + 8 <= ke; k += 8) {
            ushort_t u[8];
            #pragma unroll
            for (int j = 0; j < 8; j++)
                u[j] = hprev[(size_t)ssrc[k + j] * FIN + f];
            #pragma unroll
            for (int j = 0; j < 8; j++) {
                float xv = bf2f(u[j]);
                float4 q = qs[k + j];
                a0 += q.x * xv; a1 += q.y * xv; a2 += q.z * xv; a3 += q.w * xv;
            }
        }
        for (; k + 4 <= ke; k += 4) {
            ushort_t u[4];
            #pragma unroll
            for (int j = 0; j < 4; j++)
                u[j] = hprev[(size_t)ssrc[k + j] * FIN + f];
            #pragma unroll
            for (int j = 0; j < 4; j++) {
                float xv = bf2f(u[j]);
                float4 q = qs[k + j];
                a0 += q.x * xv; a1 += q.y * xv; a2 += q.z * xv; a3 += q.w * xv;
            }
        }
        for (; k < ke; k++) {
            float xv = bf2f(hprev[(size_t)ssrc[k] * FIN + f]);
            float4 q = qs[k];
            a0 += q.x * xv; a1 += q.y * xv; a2 += q.z * xv; a3 += q.w * xv;
        }
    }

    if (n < N_NODES) {
        size_t base = (size_t)n * (4 * FIN) + f;
        z[base]           = a0;
        z[base + FIN]     = a1;
        z[base + 2 * FIN] = a2;
        z[base + 3 * FIN] = a3;
    }
}

// ---------------- post: out[n,o] = relu( sum_k z[n,k]*Wp[k,o] + b[o] )
// MODE 2: write bf16 out + compute p_next = out @ Unext
// MODE 3: write bf16 out only

template<int FIN, int FOUT, int MODE>
__global__ __launch_bounds__(256, 4) void post_kernel(
        const float* __restrict__ z,      // [N, 4*FIN]
        const float* __restrict__ W,      // [FIN, 4*FOUT]
        const float* __restrict__ b,      // [FOUT]
        ushort_t* __restrict__ out_bf,    // [N, FOUT]
        const float* __restrict__ Unext,  // [FOUT, 4] (MODE 2)
        float* __restrict__ pnext)        // [N, 4]    (MODE 2)
{
    constexpr int K   = 4 * FIN;
    constexpr int OL  = FOUT / 4;
    constexpr int NPB = 4 * (256 / OL);
    constexpr int WSZ = FIN * 4 * FOUT;
    constexpr bool PNEXT = (MODE == 2);
    __shared__ float Wp[WSZ];           // [K][FOUT], k = h*FIN+f
    __shared__ float htile[PNEXT ? NPB * FOUT : 1];
    __shared__ float Uloc[PNEXT ? FOUT * 4 : 1];
    for (int i = threadIdx.x; i < WSZ; i += 256) {
        int f = i / (4 * FOUT);
        int r = i - f * (4 * FOUT);
        int h = r / FOUT;
        int o = r - h * FOUT;
        Wp[(h * FIN + f) * FOUT + o] = W[i];
    }
    if (PNEXT) {
        for (int i = threadIdx.x; i < FOUT * 4; i += 256) Uloc[i] = Unext[i];
    }
    __syncthreads();

    int ol = threadIdx.x % OL;
    int g  = threadIdx.x / OL;
    int n0 = blockIdx.x * NPB + g * 4;

    float4 bv = *(const float4*)(b + 4 * ol);
    float4 acc[4];
    const float* zr[4];
    #pragma unroll
    for (int j = 0; j < 4; j++) {
        acc[j] = make_float4(0.f, 0.f, 0.f, 0.f);
        int nn = n0 + j; if (nn > N_NODES - 1) nn = N_NODES - 1;
        zr[j] = z + (size_t)nn * K;
    }

    #pragma unroll 2
    for (int kq = 0; kq < K / 4; kq++) {
        float4 zv[4];
        #pragma unroll
        for (int j = 0; j < 4; j++)
            zv[j] = *(const float4*)(zr[j] + 4 * kq);
        #pragma unroll
        for (int jj = 0; jj < 4; jj++) {
            float4 wv = *(const float4*)(Wp + (4 * kq + jj) * FOUT + 4 * ol);
            #pragma unroll
            for (int j = 0; j < 4; j++) {
                float s = (&zv[j].x)[jj];
                acc[j].x += s * wv.x;
                acc[j].y += s * wv.y;
                acc[j].z += s * wv.z;
                acc[j].w += s * wv.w;
            }
        }
    }

    #pragma unroll
    for (int j = 0; j < 4; j++) {
        int nn = n0 + j;
        float4 r;
        r.x = fmaxf(acc[j].x + bv.x, 0.0f);
        r.y = fmaxf(acc[j].y + bv.y, 0.0f);
        r.z = fmaxf(acc[j].z + bv.z, 0.0f);
        r.w = fmaxf(acc[j].w + bv.w, 0.0f);
        if (PNEXT)
            *(float4*)(htile + (g * 4 + j) * FOUT + 4 * ol) = r;
        if (nn < N_NODES) {
            ushort4 u;
            u.x = f2bf(r.x); u.y = f2bf(r.y); u.z = f2bf(r.z); u.w = f2bf(r.w);
            *(ushort4*)(out_bf + (size_t)nn * FOUT + 4 * ol) = u;
        }
    }

    if (PNEXT) {
        __syncthreads();
        int tid = threadIdx.x;
        if (tid < NPB) {
            int nn = blockIdx.x * NPB + tid;
            if (nn < N_NODES) {
                float a0 = 0, a1 = 0, a2 = 0, a3 = 0;
                const float* hr = htile + tid * FOUT;
                #pragma unroll
                for (int f = 0; f < FOUT; f++) {
                    float xv = hr[f];
                    a0 += xv * Uloc[f * 4 + 0];
                    a1 += xv * Uloc[f * 4 + 1];
                    a2 += xv * Uloc[f * 4 + 2];
                    a3 += xv * Uloc[f * 4 + 3];
                }
                *(float4*)(pnext + (size_t)nn * 4) = make_float4(a0, a1, a2, a3);
            }
        }
    }
}

// ---------------- fused linear tail (bf16 input): 64->32->16->8->4->1 ----------------

__global__ __launch_bounds__(256) void tail_kernel(
        const ushort_t* __restrict__ h,   // [N, 64] bf16
        const float* __restrict__ lw1, const float* __restrict__ lb1,
        const float* __restrict__ lw2, const float* __restrict__ lb2,
        const float* __restrict__ lw3, const float* __restrict__ lb3,
        const float* __restrict__ lw4, const float* __restrict__ lb4,
        const float* __restrict__ lw5, const float* __restrict__ lb5,
        float* __restrict__ out)
{
    __shared__ float w1[64 * 32], w2[32 * 16], w3[16 * 8], w4[8 * 4], w5[4];
    __shared__ float B1[32], B2[16], B3[8], B4[4], B5[1];
    for (int i = threadIdx.x; i < 64 * 32; i += blockDim.x) w1[i] = lw1[i];
    for (int i = threadIdx.x; i < 32 * 16; i += blockDim.x) w2[i] = lw2[i];
    for (int i = threadIdx.x; i < 16 * 8;  i += blockDim.x) w3[i] = lw3[i];
    for (int i = threadIdx.x; i < 8 * 4;   i += blockDim.x) w4[i] = lw4[i];
    for (int i = threadIdx.x; i < 4;       i += blockDim.x) w5[i] = lw5[i];
    for (int i = threadIdx.x; i < 32; i += blockDim.x) B1[i] = lb1[i];
    for (int i = threadIdx.x; i < 16; i += blockDim.x) B2[i] = lb2[i];
    for (int i = threadIdx.x; i < 8;  i += blockDim.x) B3[i] = lb3[i];
    for (int i = threadIdx.x; i < 4;  i += blockDim.x) B4[i] = lb4[i];
    if (threadIdx.x == 0) B5[0] = lb5[0];
    __syncthreads();

    int n = blockIdx.x * blockDim.x + threadIdx.x;
    if (n >= N_NODES) return;

    float a[64];
    const uint4* hrow = (const uint4*)(h + (size_t)n * 64);
    #pragma unroll
    for (int j = 0; j < 8; j++) {          // 8 x uint4 = 64 bf16
        uint4 v = hrow[j];
        unpack2(v.x, a[8 * j + 0], a[8 * j + 1]);
        unpack2(v.y, a[8 * j + 2], a[8 * j + 3]);
        unpack2(v.z, a[8 * j + 4], a[8 * j + 5]);
        unpack2(v.w, a[8 * j + 6], a[8 * j + 7]);
    }

    float t1[32];
    for (int o = 0; o < 32; o++) {
        float acc = B1[o];
        #pragma unroll
        for (int i = 0; i < 64; i++) acc += a[i] * w1[i * 32 + o];
        t1[o] = fmaxf(acc, 0.0f);
    }
    float t2[16];
    for (int o = 0; o < 16; o++) {
        float acc = B2[o];
        #pragma unroll
        for (int i = 0; i < 32; i++) acc += t1[i] * w2[i * 16 + o];
        t2[o] = fmaxf(acc, 0.0f);
    }
    float t3[8];
    for (int o = 0; o < 8; o++) {
        float acc = B3[o];
        #pragma unroll
        for (int i = 0; i < 16; i++) acc += t2[i] * w3[i * 8 + o];
        t3[o] = fmaxf(acc, 0.0f);
    }
    float t4[4];
    for (int o = 0; o < 4; o++) {
        float acc = B4[o];
        #pragma unroll
        for (int i = 0; i < 8; i++) acc += t3[i] * w4[i * 4 + o];
        t4[o] = fmaxf(acc, 0.0f);
    }
    float zf = B5[0];
    #pragma unroll
    for (int i = 0; i < 4; i++) zf += t4[i] * w5[i];
    out[n] = 1.0f / (1.0f + expf(-zf));
}

// ---------------- host launch ----------------

extern "C" void kernel_launch(void* const* d_in, const int* in_sizes, int n_in,
                              void* d_out, int out_size, void* d_ws, size_t ws_size,
                              hipStream_t stream) {
    const float* x   = (const float*)d_in[0];
    const int*   ei  = (const int*)d_in[1];
    const int*   src = ei;
    const int*   dst = ei + N_EDGES;
    const float* U1 = (const float*)d_in[2];  const float* c1 = (const float*)d_in[3];
    const float* W1 = (const float*)d_in[4];  const float* b1 = (const float*)d_in[5];
    const float* U2 = (const float*)d_in[6];  const float* c2 = (const float*)d_in[7];
    const float* W2 = (const float*)d_in[8];  const float* b2 = (const float*)d_in[9];
    const float* U3 = (const float*)d_in[10]; const float* c3 = (const float*)d_in[11];
    const float* W3 = (const float*)d_in[12]; const float* b3 = (const float*)d_in[13];
    const float* lw1 = (const float*)d_in[14]; const float* lb1 = (const float*)d_in[15];
    const float* lw2 = (const float*)d_in[16]; const float* lb2 = (const float*)d_in[17];
    const float* lw3 = (const float*)d_in[18]; const float* lb3 = (const float*)d_in[19];
    const float* lw4 = (const float*)d_in[20]; const float* lb4 = (const float*)d_in[21];
    const float* lw5 = (const float*)d_in[22]; const float* lb5 = (const float*)d_in[23];

    char* ws = (char*)d_ws;
    size_t off = 0;
    auto alloc = [&](size_t bytes) -> void* {
        void* ptr = (void*)(ws + off);
        off += (bytes + 255) & ~(size_t)255;
        return ptr;
    };
    int*      bucket_cnt    = (int*)alloc((size_t)(NBKT + 1) * 4);
    int*      bucket_base   = (int*)alloc((size_t)(NBKT + 1) * 4);
    int*      bucket_cursor = (int*)alloc((size_t)NBKT * 4);
    int*      csr_tmp       = (int*)alloc((size_t)N_EDGES * 4);
    int*      rowptr        = (int*)alloc(((size_t)N_NODES + 1) * 4);
    int*      csr_src       = (int*)alloc((size_t)N_EDGES * 4);
    float*    p             = (float*)alloc((size_t)N_NODES * 4 * 4);    // [N,4]
    float*    z             = (float*)alloc((size_t)N_NODES * 128 * 4);  // [N,128] max
    ushort_t* xbf           = (ushort_t*)alloc((size_t)N_NODES * 16 * 2);
    ushort_t* h1bf          = (ushort_t*)alloc((size_t)N_NODES * 16 * 2);
    ushort_t* h2bf          = (ushort_t*)alloc((size_t)N_NODES * 32 * 2);
    ushort_t* h3bf          = (ushort_t*)alloc((size_t)N_NODES * 64 * 2);
    (void)ws_size;

    const int B = 256;
    int gN = (N_NODES + B - 1) / B;

    // ---- build dst-CSR via two-level multisplit (no per-edge global atomics) ----
    zero_int_kernel<<<(NBKT + 255) / 256, B, 0, stream>>>(bucket_cnt, NBKT);
    bhist_kernel<<<NCHUNK, B, 0, stream>>>(dst, bucket_cnt);
    bscan_kernel<<<1, 512, 0, stream>>>(bucket_cnt, bucket_base, bucket_cursor);
    partition_kernel<<<NCHUNK, B, 0, stream>>>(src, dst, bucket_cursor, csr_tmp);
    bucket_build_kernel<<<NBKT, B, 0, stream>>>(bucket_base, csr_tmp, rowptr, csr_src);

    const int ZG16 = (N_NODES + (256 / 16) - 1) / (256 / 16);   // 6250
    const int ZG32 = (N_NODES + (256 / 32) - 1) / (256 / 32);   // 12500
    const int NPB1 = 4 * (256 / (16 / 4));   // 256
    const int NPB2 = 4 * (256 / (32 / 4));   // 128
    const int NPB3 = 4 * (256 / (64 / 4));   // 64

    // ---- conv1: 16 -> 16 ----  (p1 fused with x->bf16 cast; post writes bf16 h1 + p2)
    p_cast_kernel<<<gN, B, 0, stream>>>(x, U1, p, xbf);
    zgather_bf16_kernel<16><<<ZG16, B, 0, stream>>>(rowptr, csr_src, p, c1, xbf, z);
    post_kernel<16, 16, 2><<<(N_NODES + NPB1 - 1) / NPB1, B, 0, stream>>>(
        z, W1, b1, h1bf, U2, p);

    // ---- conv2: 16 -> 32 ----  (bf16 h1 gather is L2-resident; post writes bf16 h2 + p3)
    zgather_bf16_kernel<16><<<ZG16, B, 0, stream>>>(rowptr, csr_src, p, c2, h1bf, z);
    post_kernel<16, 32, 2><<<(N_NODES + NPB2 - 1) / NPB2, B, 0, stream>>>(
        z, W2, b2, h2bf, U3, p);

    // ---- conv3: 32 -> 64 ----  (bf16 gather; post writes bf16 h3)
    zgather_bf16_kernel<32><<<ZG32, B, 0, stream>>>(rowptr, csr_src, p, c3, h2bf, z);
    post_kernel<32, 64, 3><<<(N_NODES + NPB3 - 1) / NPB3, B, 0, stream>>>(
        z, W3, b3, h3bf, nullptr, nullptr);

    // ---- tail MLP (bf16 input) ----
    tail_kernel<<<gN, B, 0, stream>>>(h3bf, lw1, lb1, lw2, lb2, lw3, lb3,
                                      lw4, lb4, lw5, lb5, (float*)d_out);
}